// Round 12
// baseline (134.384 us; speedup 1.0000x reference)
//
#include <hip/hip_runtime.h>
#include <hip/hip_bf16.h>
#include <hip/hip_fp8.h>

typedef unsigned short ushort_t;
typedef unsigned char uchar_t;
typedef __attribute__((ext_vector_type(8))) short short8;
typedef __attribute__((ext_vector_type(8))) unsigned short u16x8;
typedef __attribute__((ext_vector_type(4))) float f32x4;

#define BETA 0.4f
#define EPS_C 0.05f
#define NB 8192
#define NH 1024
#define NL 2048
#define NC 5
#define VSCALE 64.0f

static __device__ __forceinline__ float b2f(unsigned short u) {
    union { unsigned int i; float f; } x; x.i = ((unsigned int)u) << 16; return x.f;
}
static __device__ __forceinline__ unsigned short f2b(float f) {
    union { float f; unsigned int i; } x; x.f = f;
    unsigned int i = x.i;
    unsigned int r = (i + 0x7FFFu + ((i >> 16) & 1u)) >> 16;
    return (unsigned short)r;
}
static __device__ __forceinline__ uchar_t f2fp8(float f) {
    __hip_fp8_e4m3 t(f);
    return (uchar_t)t.__x;
}

static __device__ __forceinline__ void gload16(const ushort_t* g, ushort_t* l) {
    __builtin_amdgcn_global_load_lds((const __attribute__((address_space(1))) void*)g,
                                     (__attribute__((address_space(3))) void*)l, 16, 0, 0);
}
static __device__ __forceinline__ void gload16b(const uchar_t* g, uchar_t* l) {
    __builtin_amdgcn_global_load_lds((const __attribute__((address_space(1))) void*)g,
                                     (__attribute__((address_space(3))) void*)l, 16, 0, 0);
}

#define CFENCE() asm volatile("" ::: "memory")
#define MFMA16(d, a, b) __builtin_amdgcn_mfma_f32_16x16x32_bf16(a, b, d, 0, 0, 0)
#define MFMA8(d, a, b)  __builtin_amdgcn_mfma_f32_16x16x32_fp8_fp8(a, b, d, 0, 0, 0)

// ---------------- conversion kernels ----------------
__global__ __launch_bounds__(256) void cvt_kernel(const float* __restrict__ in,
                                                  ushort_t* __restrict__ out, long n) {
    long i = ((long)blockIdx.x * 256 + threadIdx.x) * 8;
    if (i >= n) return;
    const float4 a = *(const float4*)(in + i);
    const float4 b = *(const float4*)(in + i + 4);
    u16x8 o;
    o[0] = f2b(a.x); o[1] = f2b(a.y); o[2] = f2b(a.z); o[3] = f2b(a.w);
    o[4] = f2b(b.x); o[5] = f2b(b.y); o[6] = f2b(b.z); o[7] = f2b(b.w);
    *(u16x8*)(out + i) = o;
}

// W1 [2048,1024] -> W1Tb bf16 [1024,2048]  AND  W1f8 = fp8(W1*64) [2048,1024]
__global__ __launch_bounds__(256) void trans_kernel(const float* __restrict__ W1,
                                                    ushort_t* __restrict__ W1Tb,
                                                    uchar_t* __restrict__ W1f8) {
    __shared__ float tile[32][33];
    const int tx = threadIdx.x & 31, ty = threadIdx.x >> 5;
    const int k0 = blockIdx.x * 32, n0 = blockIdx.y * 32;
#pragma unroll
    for (int i = 0; i < 4; ++i) {
        const float v = W1[(size_t)(k0 + ty + i * 8) * NH + n0 + tx];
        tile[ty + i * 8][tx] = v;
        W1f8[(size_t)(k0 + ty + i * 8) * NH + n0 + tx] = f2fp8(v * VSCALE);
    }
    __syncthreads();
#pragma unroll
    for (int i = 0; i < 4; ++i)
        W1Tb[(size_t)(n0 + ty + i * 8) * NL + k0 + tx] = f2b(tile[tx][ty + i * 8]);
}

// ============ GEMM1: 128x128 tile, BK=32, 2 waves of 128x64, ~4 blocks/CU ============
// Wave tile 128x64 -> 42.7 FLOP/LDS-byte (vs 32 for 64x64). 32-MFMA bursts preserved.
// LDS: pair-packed 128B lines (2 rows x 32k); slot sl=((row&1)<<2)|fg, phys=sl^(r1&7).
__global__ __launch_bounds__(128, 2) void g128_2w(const ushort_t* __restrict__ A,
                                                  const ushort_t* __restrict__ Bt,
                                                  const float* __restrict__ b1,
                                                  ushort_t* __restrict__ hout) {
    constexpr int K  = 2048;
    constexpr int NT = K / 32;                   // 64

    __shared__ ushort_t As[2][4096];             // 128 x 32 pair-packed (8KB each)
    __shared__ ushort_t Bs[2][4096];

    const int tid = threadIdx.x;
    const int wv = tid >> 6, lane = tid & 63;    // 2 waves; wave covers all 128 rows,
    const int wn = wv;                           //   cols wn*64..+64
    const int fr = lane & 15, fg = lane >> 4;

    const int xcd = blockIdx.x & 7, loc = blockIdx.x >> 3;
    const int bm0 = (xcd * 8 + (loc >> 3)) * 128;
    const int bn0 = (loc & 7) * 128;

    const int t8 = tid >> 3, t7 = tid & 7;       // t8 = wv*8 + (lane>>3)

#define STA(BUF, KT) {                                                      \
    _Pragma("unroll") for (int j_ = 0; j_ < 4; ++j_) {                      \
        const int r1_ = j_ * 16 + t8;                                       \
        const int sl_ = t7 ^ (r1_ & 7);                                     \
        const int row_ = 2 * r1_ + (sl_ >> 2);                              \
        const int col_ = (KT) * 32 + (sl_ & 3) * 8;                         \
        gload16(A + (size_t)(bm0 + row_) * K + col_,                        \
                &As[BUF][j_ * 1024 + wv * 512]);                            \
    } }
#define STB(BUF, KT) {                                                      \
    _Pragma("unroll") for (int j_ = 0; j_ < 4; ++j_) {                      \
        const int r1_ = j_ * 16 + t8;                                       \
        const int sl_ = t7 ^ (r1_ & 7);                                     \
        const int row_ = 2 * r1_ + (sl_ >> 2);                              \
        const int col_ = (KT) * 32 + (sl_ & 3) * 8;                         \
        gload16(Bt + (size_t)(bn0 + row_) * K + col_,                       \
                &Bs[BUF][j_ * 1024 + wv * 512]);                            \
    } }

    auto ldA = [&](int buf, int mf) -> short8 {
        const int row = mf * 16 + fr;
        const int r1 = row >> 1;
        const int phys = ((((row & 1) << 2) | fg) ^ (r1 & 7));
        return *(const short8*)&As[buf][r1 * 64 + phys * 8];
    };
    auto ldB = [&](int buf, int nf) -> short8 {
        const int row = wn * 64 + nf * 16 + fr;
        const int r1 = row >> 1;
        const int phys = ((((row & 1) << 2) | fg) ^ (r1 & 7));
        return *(const short8*)&Bs[buf][r1 * 64 + phys * 8];
    };

    f32x4 acc[8][4] = {};

    STA(0, 0) STB(0, 0)
    asm volatile("s_waitcnt vmcnt(0)" ::: "memory");
    CFENCE(); __builtin_amdgcn_s_barrier(); CFENCE();

#define TILE(BUF, TT) {                                                     \
    const int t_ = (TT);                                                    \
    short8 af[8], bf[4];                                                    \
    _Pragma("unroll") for (int n_ = 0; n_ < 4; ++n_) bf[n_] = ldB(BUF, n_); \
    _Pragma("unroll") for (int m_ = 0; m_ < 8; ++m_) af[m_] = ldA(BUF, m_); \
    if (t_ + 1 < NT) { STA(BUF ^ 1, t_ + 1) STB(BUF ^ 1, t_ + 1) }          \
    CFENCE(); __builtin_amdgcn_s_barrier(); CFENCE();                       \
    __builtin_amdgcn_s_setprio(1);                                          \
    _Pragma("unroll") for (int m_ = 0; m_ < 8; ++m_)                        \
        _Pragma("unroll") for (int n_ = 0; n_ < 4; ++n_)                    \
            acc[m_][n_] = MFMA16(acc[m_][n_], af[m_], bf[n_]);              \
    __builtin_amdgcn_s_setprio(0);                                          \
    asm volatile("s_waitcnt vmcnt(0)" ::: "memory");                        \
    CFENCE(); __builtin_amdgcn_s_barrier(); CFENCE();                       \
    }

#pragma unroll 1
    for (int t = 0; t < NT; t += 2) {
        TILE(0, t)
        TILE(1, t + 1)
    }
#undef TILE
#undef STA
#undef STB

#pragma unroll
    for (int m = 0; m < 8; ++m)
#pragma unroll
        for (int n = 0; n < 4; ++n) {
            const int col = bn0 + wn * 64 + n * 16 + fr;
            const float bb = b1[col];
            const size_t rbase = (size_t)(bm0 + m * 16 + fg * 4) * NH + col;
#pragma unroll
            for (int r = 0; r < 4; ++r)
                hout[rbase + (size_t)r * NH] = f2b(tanhf(acc[m][n][r] + bb));
        }
}

// ============ GEMM2: fp8 e4m3, 128x128 dbuf (r11 proven, control) ============
__global__ __launch_bounds__(256, 4) void g2f8(const uchar_t* __restrict__ A,
                                               const uchar_t* __restrict__ Bt,
                                               float* __restrict__ partout) {
    constexpr int K  = 1024;
    constexpr int NT = K / 64;                  // 16

    __shared__ uchar_t As[2][8192];
    __shared__ uchar_t Bs[2][8192];

    const int tid = threadIdx.x;
    const int wv = tid >> 6, lane = tid & 63;
    const int wm = (wv >> 1) & 1, wn = wv & 1;
    const int fr = lane & 15, fg = lane >> 4;

    const int xcd = blockIdx.x & 7, loc = blockIdx.x >> 3;
    const int bm0 = (xcd * 8 + (loc >> 4)) * 128;
    const int bnIdx = loc & 15;
    const int bn0 = bnIdx * 128;

    const int t8 = tid >> 3, t7 = tid & 7;

#define STAF(BUF, KT) {                                                     \
    _Pragma("unroll") for (int j_ = 0; j_ < 2; ++j_) {                      \
        const int r1_ = j_ * 32 + t8;                                       \
        const int sl_ = (t7 * 2) ^ ((r1_ & 7) << 1);                        \
        const int row_ = 2 * r1_ + (sl_ >> 3);                              \
        const int cb_ = (KT) * 64 + (sl_ & 7) * 8;                          \
        gload16b(A + (size_t)(bm0 + row_) * K + cb_,                        \
                 &As[BUF][j_ * 4096 + wv * 1024]);                          \
    } }
#define STBF(BUF, KT) {                                                     \
    _Pragma("unroll") for (int j_ = 0; j_ < 2; ++j_) {                      \
        const int r1_ = j_ * 32 + t8;                                       \
        const int sl_ = (t7 * 2) ^ ((r1_ & 7) << 1);                        \
        const int row_ = 2 * r1_ + (sl_ >> 3);                              \
        const int cb_ = (KT) * 64 + (sl_ & 7) * 8;                          \
        gload16b(Bt + (size_t)(bn0 + row_) * K + cb_,                       \
                 &Bs[BUF][j_ * 4096 + wv * 1024]);                          \
    } }

    auto ldA = [&](int buf, int mf, int ks) -> long {
        const int row = wm * 64 + mf * 16 + fr;
        const int r1 = row >> 1;
        const int phys = (((row & 1) << 3) | (ks << 2) | fg) ^ ((r1 & 7) << 1);
        return *(const long*)&As[buf][r1 * 128 + phys * 8];
    };
    auto ldB = [&](int buf, int nf, int ks) -> long {
        const int row = wn * 64 + nf * 16 + fr;
        const int r1 = row >> 1;
        const int phys = (((row & 1) << 3) | (ks << 2) | fg) ^ ((r1 & 7) << 1);
        return *(const long*)&Bs[buf][r1 * 128 + phys * 8];
    };

    f32x4 acc[4][4] = {};

    STAF(0, 0) STBF(0, 0)
    asm volatile("s_waitcnt vmcnt(0)" ::: "memory");
    CFENCE(); __builtin_amdgcn_s_barrier(); CFENCE();

#define TILEF(BUF, TT) {                                                    \
    const int t_ = (TT);                                                    \
    long af[4][2], bf[4][2];                                                \
    _Pragma("unroll") for (int n_ = 0; n_ < 4; ++n_) {                      \
        bf[n_][0] = ldB(BUF, n_, 0); bf[n_][1] = ldB(BUF, n_, 1);           \
    }                                                                       \
    _Pragma("unroll") for (int m_ = 0; m_ < 4; ++m_) {                      \
        af[m_][0] = ldA(BUF, m_, 0); af[m_][1] = ldA(BUF, m_, 1);           \
    }                                                                       \
    if (t_ + 1 < NT) { STAF(BUF ^ 1, t_ + 1) STBF(BUF ^ 1, t_ + 1) }        \
    CFENCE(); __builtin_amdgcn_s_barrier(); CFENCE();                       \
    __builtin_amdgcn_s_setprio(1);                                          \
    _Pragma("unroll") for (int m_ = 0; m_ < 4; ++m_)                        \
        _Pragma("unroll") for (int n_ = 0; n_ < 4; ++n_) {                  \
            acc[m_][n_] = MFMA8(acc[m_][n_], af[m_][0], bf[n_][0]);         \
            acc[m_][n_] = MFMA8(acc[m_][n_], af[m_][1], bf[n_][1]);         \
        }                                                                   \
    __builtin_amdgcn_s_setprio(0);                                          \
    asm volatile("s_waitcnt vmcnt(0)" ::: "memory");                        \
    CFENCE(); __builtin_amdgcn_s_barrier(); CFENCE();                       \
    }

#pragma unroll 1
    for (int t = 0; t < NT; t += 2) {
        TILEF(0, t)
        TILEF(1, t + 1)
    }
#undef TILEF
#undef STAF
#undef STBF

    __syncthreads();
    float* rsum = (float*)&As[0][0];
#pragma unroll
    for (int m = 0; m < 4; ++m)
#pragma unroll
        for (int r = 0; r < 4; ++r) {
            float s = 0.f;
#pragma unroll
            for (int n = 0; n < 4; ++n) s += fabsf(acc[m][n][r]);
            s += __shfl_xor(s, 1); s += __shfl_xor(s, 2);
            s += __shfl_xor(s, 4); s += __shfl_xor(s, 8);
            if (fr == 0) rsum[wn * 128 + wm * 64 + m * 16 + fg * 4 + r] = s;
        }
    __syncthreads();
    if (tid < 128)
        partout[(size_t)bnIdx * NB + bm0 + tid] = rsum[tid] + rsum[128 + tid];
}

// ---------------- per-row kernel: logits, losses, v (fp8 out, scaled x64) ----------------
__global__ __launch_bounds__(256) void rows_kernel(const ushort_t* __restrict__ hb,
                                                   const int* __restrict__ y,
                                                   const float* __restrict__ W2,
                                                   const float* __restrict__ b2,
                                                   uchar_t* __restrict__ vb,
                                                   float4* __restrict__ rowstats) {
    __shared__ float w2t[NC][NH];
    __shared__ float b2s[NC];
    const int tid = threadIdx.x;
    for (int i = tid; i < NH * NC; i += 256) w2t[i % NC][i / NC] = W2[i];
    if (tid < NC) b2s[tid] = b2[tid];
    __syncthreads();
    const int wid = tid >> 6, lane = tid & 63;
    const int row = blockIdx.x * 4 + wid;
    const ushort_t* hrow = hb + (size_t)row * NH;
    uchar_t* vrow = vb + (size_t)row * NH;
    const int yi = y[row];
    float d0 = 0, d1 = 0, d2 = 0, d3 = 0, d4 = 0;
#pragma unroll
    for (int it = 0; it < 2; ++it) {
        const int n0 = it * 512 + lane * 8;
        u16x8 hv = *(const u16x8*)(hrow + n0);
        float hh[8];
#pragma unroll
        for (int j = 0; j < 8; ++j) hh[j] = b2f(hv[j]);
#pragma unroll
        for (int c = 0; c < NC; ++c) {
            const float4 a = *(const float4*)&w2t[c][n0];
            const float4 b = *(const float4*)&w2t[c][n0 + 4];
            float d = hh[0] * a.x; d += hh[1] * a.y; d += hh[2] * a.z; d += hh[3] * a.w;
            d += hh[4] * b.x; d += hh[5] * b.y; d += hh[6] * b.z; d += hh[7] * b.w;
            if (c == 0) d0 += d; else if (c == 1) d1 += d; else if (c == 2) d2 += d;
            else if (c == 3) d3 += d; else d4 += d;
        }
        const float4 ya = *(const float4*)&w2t[yi][n0];
        const float4 yb = *(const float4*)&w2t[yi][n0 + 4];
        const float yw[8] = { ya.x, ya.y, ya.z, ya.w, yb.x, yb.y, yb.z, yb.w };
        union { uchar_t b[8]; long l; } ov;
#pragma unroll
        for (int j = 0; j < 8; ++j)
            ov.b[j] = f2fp8((1.f - hh[j] * hh[j]) * yw[j] * VSCALE);
        *(long*)(vrow + n0) = ov.l;
    }
#pragma unroll
    for (int off = 32; off; off >>= 1) {
        d0 += __shfl_xor(d0, off); d1 += __shfl_xor(d1, off); d2 += __shfl_xor(d2, off);
        d3 += __shfl_xor(d3, off); d4 += __shfl_xor(d4, off);
    }
    if (lane == 0) {
        float lg[NC] = { d0 + b2s[0], d1 + b2s[1], d2 + b2s[2], d3 + b2s[3], d4 + b2s[4] };
        float zy = lg[yi];
        float mse = 0.f, marg = 0.f;
        int amax = 0; float best = lg[0];
#pragma unroll
        for (int c = 0; c < NC; ++c) {
            float t = lg[c] - (c == yi ? 1.f : 0.f);
            mse += t * t;
            if (c != yi) marg += fmaxf(1.f - zy + lg[c], 0.f);
            if (lg[c] > best) { best = lg[c]; amax = c; }
        }
        rowstats[row] = make_float4(zy, mse, marg, (amax == yi) ? 1.f : 0.f);
    }
}

// ---------------- reductions ----------------
__global__ __launch_bounds__(256) void reduce_rows(const float4* __restrict__ rs,
                                                   const float* __restrict__ part,
                                                   int NT, float4* __restrict__ bsums) {
    const int tid = threadIdx.x;
    const int r = blockIdx.x * 256 + tid;
    float4 v = rs[r];
    float wl1 = 0.f;
    for (int t = 0; t < NT; ++t) wl1 += part[(size_t)t * NB + r];
    wl1 *= (1.0f / (VSCALE * VSCALE));   // undo fp8 pre-scaling (64*64)
    float R = wl1 * EPS_C / (fabsf(v.x) + 1e-8f);
    float4 s = make_float4(v.y, v.z, v.w, log1pf(R));
#pragma unroll
    for (int off = 32; off; off >>= 1) {
        s.x += __shfl_down(s.x, off); s.y += __shfl_down(s.y, off);
        s.z += __shfl_down(s.z, off); s.w += __shfl_down(s.w, off);
    }
    __shared__ float4 red[4];
    if ((tid & 63) == 0) red[tid >> 6] = s;
    __syncthreads();
    if (tid == 0) {
        float4 t = red[0];
        for (int i = 1; i < 4; ++i) { t.x += red[i].x; t.y += red[i].y; t.z += red[i].z; t.w += red[i].w; }
        bsums[blockIdx.x] = t;
    }
}

__global__ void final_combine(const float4* __restrict__ bsums, int nb, float* __restrict__ out) {
    const int l = threadIdx.x;
    float4 s = (l < nb) ? bsums[l] : make_float4(0.f, 0.f, 0.f, 0.f);
#pragma unroll
    for (int off = 32; off; off >>= 1) {
        s.x += __shfl_down(s.x, off); s.y += __shfl_down(s.y, off);
        s.z += __shfl_down(s.z, off); s.w += __shfl_down(s.w, off);
    }
    if (l == 0) {
        const float Bf = (float)NB;
        out[0] = s.x / (Bf * (float)NC) + (s.y / Bf + BETA * s.w / Bf) * (s.z / Bf);
    }
}

extern "C" void kernel_launch(void* const* d_in, const int* in_sizes, int n_in,
                              void* d_out, int out_size, void* d_ws, size_t ws_size,
                              hipStream_t stream) {
    const float* x  = (const float*)d_in[0];
    const int*   y  = (const int*)d_in[1];
    const float* W1 = (const float*)d_in[2];
    const float* b1 = (const float*)d_in[3];
    const float* W2 = (const float*)d_in[4];
    const float* b2 = (const float*)d_in[5];
    float* out = (float*)d_out;

    char* ws = (char*)d_ws;
    ushort_t* W1Tb = (ushort_t*)(ws);                           // 4MB
    uchar_t*  W1f8 = (uchar_t*)(ws + (4ul << 20));              // 2MB
    ushort_t* xb   = (ushort_t*)(ws + (8ul << 20));             // 32MB
    ushort_t* hb   = (ushort_t*)(ws + (40ul << 20));            // 16MB
    uchar_t*  vf8  = (uchar_t*)(ws + (56ul << 20));             // 8MB
    float4*   rowstats = (float4*)(ws + (72ul << 20));          // 128KB
    float*    part = (float*)(ws + (72ul << 20) + (1ul << 20)); // 512KB
    float4*   bsums = (float4*)(ws + (74ul << 20));             // 512B

    // 1. conversions
    cvt_kernel<<<(NB * (long)NL) / (256 * 8), 256, 0, stream>>>(x, xb, (long)NB * NL);
    trans_kernel<<<dim3(NL / 32, NH / 32), 256, 0, stream>>>(W1, W1Tb, W1f8);

    // 2. GEMM1 (2-wave 128x64 wave tiles, BK=32): h = tanh(x @ W1 + b1)
    g128_2w<<<512, 128, 0, stream>>>(xb, W1Tb, b1, hb);

    // 3. per-row: logits/mse/margin/zy/correct + v (fp8, x64)
    rows_kernel<<<NB / 4, 256, 0, stream>>>(hb, y, W2, b2, vf8, rowstats);

    // 4. GEMM2 (fp8): g = v @ W1^T, row |.| partials
    g2f8<<<1024, 256, 0, stream>>>(vf8, W1f8, part);

    // 5. reductions
    reduce_rows<<<NB / 256, 256, 0, stream>>>(rowstats, part, NL / 128, bsums);
    final_combine<<<1, 64, 0, stream>>>(bsums, NB / 256, out);
}

// Round 13
// 106.736 us; speedup vs baseline: 1.2590x; 1.2590x over previous
//
#include <hip/hip_runtime.h>
#include <hip/hip_bf16.h>

typedef unsigned short ushort_t;
typedef unsigned char uchar_t;
typedef __attribute__((ext_vector_type(8))) short short8;
typedef __attribute__((ext_vector_type(8))) unsigned short u16x8;
typedef __attribute__((ext_vector_type(4))) float f32x4;
typedef __attribute__((ext_vector_type(4))) int i32x4;

#define BETA 0.4f
#define EPS_C 0.05f
#define NB 8192
#define NH 1024
#define NL 2048
#define NC 5
#define VS_I8 800.0f
#define WS_I8 1200.0f

static __device__ __forceinline__ float b2f(unsigned short u) {
    union { unsigned int i; float f; } x; x.i = ((unsigned int)u) << 16; return x.f;
}
static __device__ __forceinline__ unsigned short f2b(float f) {
    union { float f; unsigned int i; } x; x.f = f;
    unsigned int i = x.i;
    unsigned int r = (i + 0x7FFFu + ((i >> 16) & 1u)) >> 16;
    return (unsigned short)r;
}
static __device__ __forceinline__ char f2i8(float f, float s) {
    float q = rintf(f * s);
    q = fminf(127.f, fmaxf(-127.f, q));
    return (char)(int)q;
}

static __device__ __forceinline__ void gload16(const ushort_t* g, ushort_t* l) {
    __builtin_amdgcn_global_load_lds((const __attribute__((address_space(1))) void*)g,
                                     (__attribute__((address_space(3))) void*)l, 16, 0, 0);
}
static __device__ __forceinline__ void gload16b(const uchar_t* g, uchar_t* l) {
    __builtin_amdgcn_global_load_lds((const __attribute__((address_space(1))) void*)g,
                                     (__attribute__((address_space(3))) void*)l, 16, 0, 0);
}

#define CFENCE() asm volatile("" ::: "memory")
#define MFMA16(d, a, b) __builtin_amdgcn_mfma_f32_16x16x32_bf16(a, b, d, 0, 0, 0)
#define MFMAI8(d, a, b) __builtin_amdgcn_mfma_i32_16x16x64_i8(a, b, d, 0, 0, 0)

// ---------------- conversion kernels ----------------
__global__ __launch_bounds__(256) void cvt_kernel(const float* __restrict__ in,
                                                  ushort_t* __restrict__ out, long n) {
    long i = ((long)blockIdx.x * 256 + threadIdx.x) * 8;
    if (i >= n) return;
    const float4 a = *(const float4*)(in + i);
    const float4 b = *(const float4*)(in + i + 4);
    u16x8 o;
    o[0] = f2b(a.x); o[1] = f2b(a.y); o[2] = f2b(a.z); o[3] = f2b(a.w);
    o[4] = f2b(b.x); o[5] = f2b(b.y); o[6] = f2b(b.z); o[7] = f2b(b.w);
    *(u16x8*)(out + i) = o;
}

// W1 [2048,1024] -> W1Tb bf16 [1024,2048]  AND  W1i8 = i8(W1*1200) [2048,1024]
__global__ __launch_bounds__(256) void trans_kernel(const float* __restrict__ W1,
                                                    ushort_t* __restrict__ W1Tb,
                                                    char* __restrict__ W1i8) {
    __shared__ float tile[32][33];
    const int tx = threadIdx.x & 31, ty = threadIdx.x >> 5;
    const int k0 = blockIdx.x * 32, n0 = blockIdx.y * 32;
#pragma unroll
    for (int i = 0; i < 4; ++i) {
        const float v = W1[(size_t)(k0 + ty + i * 8) * NH + n0 + tx];
        tile[ty + i * 8][tx] = v;
        W1i8[(size_t)(k0 + ty + i * 8) * NH + n0 + tx] = f2i8(v, WS_I8);
    }
    __syncthreads();
#pragma unroll
    for (int i = 0; i < 4; ++i)
        W1Tb[(size_t)(n0 + ty + i * 8) * NL + k0 + tx] = f2b(tile[tx][ty + i * 8]);
}

// ============ GEMM1: r9/r11-proven 128x128 dbuf bf16, 2 blocks/CU ============
__global__ __launch_bounds__(256, 2) void g128_1(const ushort_t* __restrict__ A,
                                                 const ushort_t* __restrict__ Bt,
                                                 const float* __restrict__ b1,
                                                 ushort_t* __restrict__ hout) {
    constexpr int K  = 2048;
    constexpr int NT = K / 64;

    __shared__ ushort_t As[2][8192];
    __shared__ ushort_t Bs[2][8192];

    const int tid = threadIdx.x;
    const int wv = tid >> 6, lane = tid & 63;
    const int wm = (wv >> 1) & 1, wn = wv & 1;
    const int fr = lane & 15, fg = lane >> 4;

    const int xcd = blockIdx.x & 7, loc = blockIdx.x >> 3;
    const int bm0 = (xcd * 8 + (loc >> 3)) * 128;
    const int bn0 = (loc & 7) * 128;

    const int srow = lane >> 3;
    const int scol = ((lane & 7) ^ srow) << 3;

#define STA(BUF, KT) {                                                      \
    _Pragma("unroll") for (int c_ = 0; c_ < 4; ++c_) {                      \
        const int row_ = c_ * 32 + wv * 8 + srow;                           \
        gload16(A + (size_t)(bm0 + row_) * K + (KT) * 64 + scol,            \
                &As[BUF][c_ * 2048 + wv * 512]);                            \
    } }
#define STB(BUF, KT) {                                                      \
    _Pragma("unroll") for (int c_ = 0; c_ < 4; ++c_) {                      \
        const int row_ = c_ * 32 + wv * 8 + srow;                           \
        gload16(Bt + (size_t)(bn0 + row_) * K + (KT) * 64 + scol,           \
                &Bs[BUF][c_ * 2048 + wv * 512]);                            \
    } }

    auto ldA = [&](int buf, int mf, int ks) -> short8 {
        const int row = wm * 64 + mf * 16 + fr;
        const int slot = ((ks << 2) + fg) ^ (row & 7);
        return *(const short8*)&As[buf][row * 64 + slot * 8];
    };
    auto ldB = [&](int buf, int nf, int ks) -> short8 {
        const int row = wn * 64 + nf * 16 + fr;
        const int slot = ((ks << 2) + fg) ^ (row & 7);
        return *(const short8*)&Bs[buf][row * 64 + slot * 8];
    };

    f32x4 acc[4][4] = {};

    STA(0, 0) STB(0, 0)
    asm volatile("s_waitcnt vmcnt(0)" ::: "memory");
    CFENCE(); __builtin_amdgcn_s_barrier(); CFENCE();

#define TILE(BUF, TT) {                                                     \
    const int t_ = (TT);                                                    \
    short8 af[4][2], bf[4][2];                                              \
    _Pragma("unroll") for (int n_ = 0; n_ < 4; ++n_) {                      \
        bf[n_][0] = ldB(BUF, n_, 0); bf[n_][1] = ldB(BUF, n_, 1);           \
    }                                                                       \
    _Pragma("unroll") for (int m_ = 0; m_ < 4; ++m_) {                      \
        af[m_][0] = ldA(BUF, m_, 0); af[m_][1] = ldA(BUF, m_, 1);           \
    }                                                                       \
    if (t_ + 1 < NT) { STA(BUF ^ 1, t_ + 1) STB(BUF ^ 1, t_ + 1) }          \
    CFENCE(); __builtin_amdgcn_s_barrier(); CFENCE();                       \
    __builtin_amdgcn_s_setprio(1);                                          \
    _Pragma("unroll") for (int m_ = 0; m_ < 4; ++m_)                        \
        _Pragma("unroll") for (int n_ = 0; n_ < 4; ++n_) {                  \
            acc[m_][n_] = MFMA16(acc[m_][n_], af[m_][0], bf[n_][0]);        \
            acc[m_][n_] = MFMA16(acc[m_][n_], af[m_][1], bf[n_][1]);        \
        }                                                                   \
    __builtin_amdgcn_s_setprio(0);                                          \
    asm volatile("s_waitcnt vmcnt(0)" ::: "memory");                        \
    CFENCE(); __builtin_amdgcn_s_barrier(); CFENCE();                       \
    }

#pragma unroll 1
    for (int t = 0; t < NT; t += 2) {
        TILE(0, t)
        TILE(1, t + 1)
    }
#undef TILE
#undef STA
#undef STB

#pragma unroll
    for (int m = 0; m < 4; ++m)
#pragma unroll
        for (int n = 0; n < 4; ++n) {
            const int col = bn0 + wn * 64 + n * 16 + fr;
            const float bb = b1[col];
            const size_t rbase = (size_t)(bm0 + wm * 64 + m * 16 + fg * 4) * NH + col;
#pragma unroll
            for (int r = 0; r < 4; ++r)
                hout[rbase + (size_t)r * NH] = f2b(tanhf(acc[m][n][r] + bb));
        }
}

// ============ GEMM2: int8 16x16x64, same proven container as g2f8, 4 blocks/CU ============
// A = vi8 [8192,1024] (v*800), Bt = W1i8 [2048,1024] (W1*1200). i32 exact accum.
// LDS: pair-packed 128B lines; 8B logical slots sl=((row&1)<<3)|(kchunk), phys=sl^((r1&7)<<1).
// i8 fragment = 16B (K=64): logical slots {(row&1)<<3|(fg<<1), +1} -> phys stays 16B-aligned.
__global__ __launch_bounds__(256, 4) void g2i8(const char* __restrict__ A,
                                               const char* __restrict__ Bt,
                                               float* __restrict__ partout) {
    constexpr int K  = 1024;
    constexpr int NT = K / 64;                  // 16

    __shared__ uchar_t As[2][8192];             // 128 rows x 64B (8KB each buf)
    __shared__ uchar_t Bs[2][8192];

    const int tid = threadIdx.x;
    const int wv = tid >> 6, lane = tid & 63;
    const int wm = (wv >> 1) & 1, wn = wv & 1;  // wave tile 64x64
    const int fr = lane & 15, fg = lane >> 4;

    const int xcd = blockIdx.x & 7, loc = blockIdx.x >> 3;
    const int bm0 = (xcd * 8 + (loc >> 4)) * 128;
    const int bnIdx = loc & 15;
    const int bn0 = bnIdx * 128;

    const int t8 = tid >> 3, t7 = tid & 7;

#define STAF(BUF, KT) {                                                     \
    _Pragma("unroll") for (int j_ = 0; j_ < 2; ++j_) {                      \
        const int r1_ = j_ * 32 + t8;                                       \
        const int sl_ = (t7 * 2) ^ ((r1_ & 7) << 1);                        \
        const int row_ = 2 * r1_ + (sl_ >> 3);                              \
        const int cb_ = (KT) * 64 + (sl_ & 7) * 8;                          \
        gload16b((const uchar_t*)A + (size_t)(bm0 + row_) * K + cb_,        \
                 &As[BUF][j_ * 4096 + wv * 1024]);                          \
    } }
#define STBF(BUF, KT) {                                                     \
    _Pragma("unroll") for (int j_ = 0; j_ < 2; ++j_) {                      \
        const int r1_ = j_ * 32 + t8;                                       \
        const int sl_ = (t7 * 2) ^ ((r1_ & 7) << 1);                        \
        const int row_ = 2 * r1_ + (sl_ >> 3);                              \
        const int cb_ = (KT) * 64 + (sl_ & 7) * 8;                          \
        gload16b((const uchar_t*)Bt + (size_t)(bn0 + row_) * K + cb_,       \
                 &Bs[BUF][j_ * 4096 + wv * 1024]);                          \
    } }

    auto ldA = [&](int buf, int mf) -> i32x4 {
        const int row = wm * 64 + mf * 16 + fr;
        const int r1 = row >> 1;
        const int phys = (((row & 1) << 3) | (fg << 1)) ^ ((r1 & 7) << 1);
        return *(const i32x4*)&As[buf][r1 * 128 + phys * 8];
    };
    auto ldB = [&](int buf, int nf) -> i32x4 {
        const int row = wn * 64 + nf * 16 + fr;
        const int r1 = row >> 1;
        const int phys = (((row & 1) << 3) | (fg << 1)) ^ ((r1 & 7) << 1);
        return *(const i32x4*)&Bs[buf][r1 * 128 + phys * 8];
    };

    i32x4 acc[4][4] = {};

    STAF(0, 0) STBF(0, 0)
    asm volatile("s_waitcnt vmcnt(0)" ::: "memory");
    CFENCE(); __builtin_amdgcn_s_barrier(); CFENCE();

#define TILEI(BUF, TT) {                                                    \
    const int t_ = (TT);                                                    \
    i32x4 af[4], bf[4];                                                     \
    _Pragma("unroll") for (int n_ = 0; n_ < 4; ++n_) bf[n_] = ldB(BUF, n_); \
    _Pragma("unroll") for (int m_ = 0; m_ < 4; ++m_) af[m_] = ldA(BUF, m_); \
    if (t_ + 1 < NT) { STAF(BUF ^ 1, t_ + 1) STBF(BUF ^ 1, t_ + 1) }        \
    CFENCE(); __builtin_amdgcn_s_barrier(); CFENCE();                       \
    __builtin_amdgcn_s_setprio(1);                                          \
    _Pragma("unroll") for (int m_ = 0; m_ < 4; ++m_)                        \
        _Pragma("unroll") for (int n_ = 0; n_ < 4; ++n_)                    \
            acc[m_][n_] = MFMAI8(acc[m_][n_], af[m_], bf[n_]);              \
    __builtin_amdgcn_s_setprio(0);                                          \
    asm volatile("s_waitcnt vmcnt(0)" ::: "memory");                        \
    CFENCE(); __builtin_amdgcn_s_barrier(); CFENCE();                       \
    }

#pragma unroll 1
    for (int t = 0; t < NT; t += 2) {
        TILEI(0, t)
        TILEI(1, t + 1)
    }
#undef TILEI
#undef STAF
#undef STBF

    __syncthreads();
    float* rsum = (float*)&As[0][0];
#pragma unroll
    for (int m = 0; m < 4; ++m)
#pragma unroll
        for (int r = 0; r < 4; ++r) {
            float s = 0.f;
#pragma unroll
            for (int n = 0; n < 4; ++n) s += fabsf((float)acc[m][n][r]);
            s += __shfl_xor(s, 1); s += __shfl_xor(s, 2);
            s += __shfl_xor(s, 4); s += __shfl_xor(s, 8);
            if (fr == 0) rsum[wn * 128 + wm * 64 + m * 16 + fg * 4 + r] = s;
        }
    __syncthreads();
    if (tid < 128)
        partout[(size_t)bnIdx * NB + bm0 + tid] = rsum[tid] + rsum[128 + tid];
}

// ---------------- per-row kernel: logits, losses, v (i8 out, scaled x800) ----------------
__global__ __launch_bounds__(256) void rows_kernel(const ushort_t* __restrict__ hb,
                                                   const int* __restrict__ y,
                                                   const float* __restrict__ W2,
                                                   const float* __restrict__ b2,
                                                   char* __restrict__ vb,
                                                   float4* __restrict__ rowstats) {
    __shared__ float w2t[NC][NH];
    __shared__ float b2s[NC];
    const int tid = threadIdx.x;
    for (int i = tid; i < NH * NC; i += 256) w2t[i % NC][i / NC] = W2[i];
    if (tid < NC) b2s[tid] = b2[tid];
    __syncthreads();
    const int wid = tid >> 6, lane = tid & 63;
    const int row = blockIdx.x * 4 + wid;
    const ushort_t* hrow = hb + (size_t)row * NH;
    char* vrow = vb + (size_t)row * NH;
    const int yi = y[row];
    float d0 = 0, d1 = 0, d2 = 0, d3 = 0, d4 = 0;
#pragma unroll
    for (int it = 0; it < 2; ++it) {
        const int n0 = it * 512 + lane * 8;
        u16x8 hv = *(const u16x8*)(hrow + n0);
        float hh[8];
#pragma unroll
        for (int j = 0; j < 8; ++j) hh[j] = b2f(hv[j]);
#pragma unroll
        for (int c = 0; c < NC; ++c) {
            const float4 a = *(const float4*)&w2t[c][n0];
            const float4 b = *(const float4*)&w2t[c][n0 + 4];
            float d = hh[0] * a.x; d += hh[1] * a.y; d += hh[2] * a.z; d += hh[3] * a.w;
            d += hh[4] * b.x; d += hh[5] * b.y; d += hh[6] * b.z; d += hh[7] * b.w;
            if (c == 0) d0 += d; else if (c == 1) d1 += d; else if (c == 2) d2 += d;
            else if (c == 3) d3 += d; else d4 += d;
        }
        const float4 ya = *(const float4*)&w2t[yi][n0];
        const float4 yb = *(const float4*)&w2t[yi][n0 + 4];
        const float yw[8] = { ya.x, ya.y, ya.z, ya.w, yb.x, yb.y, yb.z, yb.w };
        union { char b[8]; long l; } ov;
#pragma unroll
        for (int j = 0; j < 8; ++j)
            ov.b[j] = f2i8((1.f - hh[j] * hh[j]) * yw[j], VS_I8);
        *(long*)(vrow + n0) = ov.l;
    }
#pragma unroll
    for (int off = 32; off; off >>= 1) {
        d0 += __shfl_xor(d0, off); d1 += __shfl_xor(d1, off); d2 += __shfl_xor(d2, off);
        d3 += __shfl_xor(d3, off); d4 += __shfl_xor(d4, off);
    }
    if (lane == 0) {
        float lg[NC] = { d0 + b2s[0], d1 + b2s[1], d2 + b2s[2], d3 + b2s[3], d4 + b2s[4] };
        float zy = lg[yi];
        float mse = 0.f, marg = 0.f;
        int amax = 0; float best = lg[0];
#pragma unroll
        for (int c = 0; c < NC; ++c) {
            float t = lg[c] - (c == yi ? 1.f : 0.f);
            mse += t * t;
            if (c != yi) marg += fmaxf(1.f - zy + lg[c], 0.f);
            if (lg[c] > best) { best = lg[c]; amax = c; }
        }
        rowstats[row] = make_float4(zy, mse, marg, (amax == yi) ? 1.f : 0.f);
    }
}

// ---------------- reductions ----------------
__global__ __launch_bounds__(256) void reduce_rows(const float4* __restrict__ rs,
                                                   const float* __restrict__ part,
                                                   int NT, float4* __restrict__ bsums) {
    const int tid = threadIdx.x;
    const int r = blockIdx.x * 256 + tid;
    float4 v = rs[r];
    float wl1 = 0.f;
    for (int t = 0; t < NT; ++t) wl1 += part[(size_t)t * NB + r];
    wl1 *= (1.0f / (VS_I8 * WS_I8));   // undo i8 quantization scales
    float R = wl1 * EPS_C / (fabsf(v.x) + 1e-8f);
    float4 s = make_float4(v.y, v.z, v.w, log1pf(R));
#pragma unroll
    for (int off = 32; off; off >>= 1) {
        s.x += __shfl_down(s.x, off); s.y += __shfl_down(s.y, off);
        s.z += __shfl_down(s.z, off); s.w += __shfl_down(s.w, off);
    }
    __shared__ float4 red[4];
    if ((tid & 63) == 0) red[tid >> 6] = s;
    __syncthreads();
    if (tid == 0) {
        float4 t = red[0];
        for (int i = 1; i < 4; ++i) { t.x += red[i].x; t.y += red[i].y; t.z += red[i].z; t.w += red[i].w; }
        bsums[blockIdx.x] = t;
    }
}

__global__ void final_combine(const float4* __restrict__ bsums, int nb, float* __restrict__ out) {
    const int l = threadIdx.x;
    float4 s = (l < nb) ? bsums[l] : make_float4(0.f, 0.f, 0.f, 0.f);
#pragma unroll
    for (int off = 32; off; off >>= 1) {
        s.x += __shfl_down(s.x, off); s.y += __shfl_down(s.y, off);
        s.z += __shfl_down(s.z, off); s.w += __shfl_down(s.w, off);
    }
    if (l == 0) {
        const float Bf = (float)NB;
        out[0] = s.x / (Bf * (float)NC) + (s.y / Bf + BETA * s.w / Bf) * (s.z / Bf);
    }
}

extern "C" void kernel_launch(void* const* d_in, const int* in_sizes, int n_in,
                              void* d_out, int out_size, void* d_ws, size_t ws_size,
                              hipStream_t stream) {
    const float* x  = (const float*)d_in[0];
    const int*   y  = (const int*)d_in[1];
    const float* W1 = (const float*)d_in[2];
    const float* b1 = (const float*)d_in[3];
    const float* W2 = (const float*)d_in[4];
    const float* b2 = (const float*)d_in[5];
    float* out = (float*)d_out;

    char* ws = (char*)d_ws;
    ushort_t* W1Tb = (ushort_t*)(ws);                           // 4MB
    char*     W1i8 = (char*)(ws + (4ul << 20));                 // 2MB
    ushort_t* xb   = (ushort_t*)(ws + (8ul << 20));             // 32MB
    ushort_t* hb   = (ushort_t*)(ws + (40ul << 20));            // 16MB
    char*     vi8  = (char*)(ws + (56ul << 20));                // 8MB
    float4*   rowstats = (float4*)(ws + (72ul << 20));          // 128KB
    float*    part = (float*)(ws + (72ul << 20) + (1ul << 20)); // 512KB
    float4*   bsums = (float4*)(ws + (74ul << 20));             // 512B

    // 1. conversions
    cvt_kernel<<<(NB * (long)NL) / (256 * 8), 256, 0, stream>>>(x, xb, (long)NB * NL);
    trans_kernel<<<dim3(NL / 32, NH / 32), 256, 0, stream>>>(W1, W1Tb, W1i8);

    // 2. GEMM1 (bf16, proven): h = tanh(x @ W1 + b1)
    g128_1<<<512, 256, 0, stream>>>(xb, W1Tb, b1, hb);

    // 3. per-row: logits/mse/margin/zy/correct + v (i8, x800)
    rows_kernel<<<NB / 4, 256, 0, stream>>>(hb, y, W2, b2, vi8, rowstats);

    // 4. GEMM2 (i8 16x16x64): g = v @ W1^T, row |.| partials
    g2i8<<<1024, 256, 0, stream>>>(vi8, W1i8, part);

    // 5. reductions
    reduce_rows<<<NB / 256, 256, 0, stream>>>(rowstats, part, NL / 128, bsums);
    final_combine<<<1, 64, 0, stream>>>(bsums, NB / 256, out);
}

// Round 14
// 104.678 us; speedup vs baseline: 1.2838x; 1.0197x over previous
//
#include <hip/hip_runtime.h>
#include <hip/hip_bf16.h>

typedef unsigned short ushort_t;
typedef unsigned char uchar_t;
typedef __attribute__((ext_vector_type(8))) short short8;
typedef __attribute__((ext_vector_type(8))) unsigned short u16x8;
typedef __attribute__((ext_vector_type(4))) float f32x4;
typedef __attribute__((ext_vector_type(4))) int i32x4;
typedef __attribute__((ext_vector_type(4))) unsigned int u32x4;

#define BETA 0.4f
#define EPS_C 0.05f
#define NB 8192
#define NH 1024
#define NL 2048
#define NC 5
#define VS_I8 800.0f
#define WS_I8 1200.0f

static __device__ __forceinline__ float b2f(unsigned short u) {
    union { unsigned int i; float f; } x; x.i = ((unsigned int)u) << 16; return x.f;
}
static __device__ __forceinline__ unsigned short f2b(float f) {
    union { float f; unsigned int i; } x; x.f = f;
    unsigned int i = x.i;
    unsigned int r = (i + 0x7FFFu + ((i >> 16) & 1u)) >> 16;
    return (unsigned short)r;
}
static __device__ __forceinline__ char f2i8(float f, float s) {
    float q = rintf(f * s);
    q = fminf(127.f, fmaxf(-127.f, q));
    return (char)(int)q;
}
static __device__ __forceinline__ unsigned int cvtpk(float lo, float hi) {
    unsigned int r;
    asm("v_cvt_pk_bf16_f32 %0, %1, %2" : "=v"(r) : "v"(lo), "v"(hi));
    return r;
}

static __device__ __forceinline__ void gload16(const ushort_t* g, ushort_t* l) {
    __builtin_amdgcn_global_load_lds((const __attribute__((address_space(1))) void*)g,
                                     (__attribute__((address_space(3))) void*)l, 16, 0, 0);
}
static __device__ __forceinline__ void gload16b(const uchar_t* g, uchar_t* l) {
    __builtin_amdgcn_global_load_lds((const __attribute__((address_space(1))) void*)g,
                                     (__attribute__((address_space(3))) void*)l, 16, 0, 0);
}

#define CFENCE() asm volatile("" ::: "memory")
#define MFMA16(d, a, b) __builtin_amdgcn_mfma_f32_16x16x32_bf16(a, b, d, 0, 0, 0)
#define MFMAI8(d, a, b) __builtin_amdgcn_mfma_i32_16x16x64_i8(a, b, d, 0, 0, 0)

// W1 [2048,1024] -> W1Tb bf16 [1024,2048]  AND  W1i8 = i8(W1*1200) [2048,1024]
__global__ __launch_bounds__(256) void trans_kernel(const float* __restrict__ W1,
                                                    ushort_t* __restrict__ W1Tb,
                                                    char* __restrict__ W1i8) {
    __shared__ float tile[32][33];
    const int tx = threadIdx.x & 31, ty = threadIdx.x >> 5;
    const int k0 = blockIdx.x * 32, n0 = blockIdx.y * 32;
#pragma unroll
    for (int i = 0; i < 4; ++i) {
        const float v = W1[(size_t)(k0 + ty + i * 8) * NH + n0 + tx];
        tile[ty + i * 8][tx] = v;
        W1i8[(size_t)(k0 + ty + i * 8) * NH + n0 + tx] = f2i8(v, WS_I8);
    }
    __syncthreads();
#pragma unroll
    for (int i = 0; i < 4; ++i)
        W1Tb[(size_t)(n0 + ty + i * 8) * NL + k0 + tx] = f2b(tile[tx][ty + i * 8]);
}

// ============ GEMM1: 128x128 dbuf, fused f32->bf16 A-staging (reg-staged) ============
// A = x [8192,2048] f32 read directly; converted in-register via v_cvt_pk_bf16_f32 and
// ds_write'd to the SAME linear LDS image the proven gload_lds staging produced.
__global__ __launch_bounds__(256, 2) void g128_1f(const float* __restrict__ X,
                                                  const ushort_t* __restrict__ Bt,
                                                  const float* __restrict__ b1,
                                                  ushort_t* __restrict__ hout) {
    constexpr int K  = 2048;
    constexpr int NT = K / 64;          // 32

    __shared__ ushort_t As[2][8192];    // 128 x 64 bf16, 128B rows, XOR-swz slots
    __shared__ ushort_t Bs[2][8192];

    const int tid = threadIdx.x;
    const int wv = tid >> 6, lane = tid & 63;
    const int wm = (wv >> 1) & 1, wn = wv & 1;
    const int fr = lane & 15, fg = lane >> 4;

    const int xcd = blockIdx.x & 7, loc = blockIdx.x >> 3;
    const int bm0 = (xcd * 8 + (loc >> 3)) * 128;
    const int bn0 = (loc & 7) * 128;

    const int srow = lane >> 3;
    const int scolb = ((lane & 7) ^ srow) << 3;   // bf16-elem col (B staging)
    // A source: same swizzled coords, f32 elems (8 f32 = one 16B bf16 chunk)
    const int scolf = ((lane & 7) ^ srow) * 8;

    // B staging via global_load_lds (unchanged, proven)
#define STB(BUF, KT) {                                                      \
    _Pragma("unroll") for (int c_ = 0; c_ < 4; ++c_) {                      \
        const int row_ = c_ * 32 + wv * 8 + srow;                           \
        gload16(Bt + (size_t)(bn0 + row_) * K + (KT) * 64 + scolb,          \
                &Bs[BUF][c_ * 2048 + wv * 512]);                            \
    } }
    // A: issue f32 loads into regs (held across MFMA)
#define LDX(XA, KT) {                                                       \
    _Pragma("unroll") for (int c_ = 0; c_ < 4; ++c_) {                      \
        const int row_ = c_ * 32 + wv * 8 + srow;                           \
        const float* p_ = X + (size_t)(bm0 + row_) * K + (KT) * 64 + scolf; \
        XA[c_][0] = *(const float4*)p_;                                     \
        XA[c_][1] = *(const float4*)(p_ + 4);                               \
    } }
    // A: convert + linear ds_write (identical LDS image to gload_lds staging)
#define WRX(BUF, XA) {                                                      \
    _Pragma("unroll") for (int c_ = 0; c_ < 4; ++c_) {                      \
        u32x4 w_;                                                           \
        w_[0] = cvtpk(XA[c_][0].x, XA[c_][0].y);                            \
        w_[1] = cvtpk(XA[c_][0].z, XA[c_][0].w);                            \
        w_[2] = cvtpk(XA[c_][1].x, XA[c_][1].y);                            \
        w_[3] = cvtpk(XA[c_][1].z, XA[c_][1].w);                            \
        *(u32x4*)&As[BUF][c_ * 2048 + wv * 512 + lane * 8] = w_;            \
    } }

    auto ldA = [&](int buf, int mf, int ks) -> short8 {
        const int row = wm * 64 + mf * 16 + fr;
        const int slot = ((ks << 2) + fg) ^ (row & 7);
        return *(const short8*)&As[buf][row * 64 + slot * 8];
    };
    auto ldB = [&](int buf, int nf, int ks) -> short8 {
        const int row = wn * 64 + nf * 16 + fr;
        const int slot = ((ks << 2) + fg) ^ (row & 7);
        return *(const short8*)&Bs[buf][row * 64 + slot * 8];
    };

    f32x4 acc[4][4] = {};
    float4 xa[4][2];

    // prologue: tile 0
    LDX(xa, 0)
    STB(0, 0)
    asm volatile("s_waitcnt vmcnt(0)" ::: "memory");
    WRX(0, xa)
    asm volatile("s_waitcnt lgkmcnt(0)" ::: "memory");
    CFENCE(); __builtin_amdgcn_s_barrier(); CFENCE();

#define TILE(BUF, TT) {                                                     \
    const int t_ = (TT);                                                    \
    const bool more = (t_ + 1 < NT);                                        \
    short8 af[4][2], bf[4][2];                                              \
    _Pragma("unroll") for (int n_ = 0; n_ < 4; ++n_) {                      \
        bf[n_][0] = ldB(BUF, n_, 0); bf[n_][1] = ldB(BUF, n_, 1);           \
    }                                                                       \
    _Pragma("unroll") for (int m_ = 0; m_ < 4; ++m_) {                      \
        af[m_][0] = ldA(BUF, m_, 0); af[m_][1] = ldA(BUF, m_, 1);           \
    }                                                                       \
    if (more) { LDX(xa, t_ + 1) STB(BUF ^ 1, t_ + 1) }                      \
    CFENCE(); __builtin_amdgcn_s_barrier(); CFENCE();                       \
    __builtin_amdgcn_s_setprio(1);                                          \
    _Pragma("unroll") for (int m_ = 0; m_ < 4; ++m_)                        \
        _Pragma("unroll") for (int n_ = 0; n_ < 4; ++n_) {                  \
            acc[m_][n_] = MFMA16(acc[m_][n_], af[m_][0], bf[n_][0]);        \
            acc[m_][n_] = MFMA16(acc[m_][n_], af[m_][1], bf[n_][1]);        \
        }                                                                   \
    __builtin_amdgcn_s_setprio(0);                                          \
    asm volatile("s_waitcnt vmcnt(0)" ::: "memory");                        \
    if (more) { WRX(BUF ^ 1, xa) }                                          \
    asm volatile("s_waitcnt lgkmcnt(0)" ::: "memory");                      \
    CFENCE(); __builtin_amdgcn_s_barrier(); CFENCE();                       \
    }

#pragma unroll 1
    for (int t = 0; t < NT; t += 2) {
        TILE(0, t)
        TILE(1, t + 1)
    }
#undef TILE
#undef STB
#undef LDX
#undef WRX

#pragma unroll
    for (int m = 0; m < 4; ++m)
#pragma unroll
        for (int n = 0; n < 4; ++n) {
            const int col = bn0 + wn * 64 + n * 16 + fr;
            const float bb = b1[col];
            const size_t rbase = (size_t)(bm0 + wm * 64 + m * 16 + fg * 4) * NH + col;
#pragma unroll
            for (int r = 0; r < 4; ++r)
                hout[rbase + (size_t)r * NH] = f2b(tanhf(acc[m][n][r] + bb));
        }
}

// ============ GEMM2: int8 16x16x64 (r13 proven) ============
__global__ __launch_bounds__(256, 4) void g2i8(const char* __restrict__ A,
                                               const char* __restrict__ Bt,
                                               float* __restrict__ partout) {
    constexpr int K  = 1024;
    constexpr int NT = K / 64;

    __shared__ uchar_t As[2][8192];
    __shared__ uchar_t Bs[2][8192];

    const int tid = threadIdx.x;
    const int wv = tid >> 6, lane = tid & 63;
    const int wm = (wv >> 1) & 1, wn = wv & 1;
    const int fr = lane & 15, fg = lane >> 4;

    const int xcd = blockIdx.x & 7, loc = blockIdx.x >> 3;
    const int bm0 = (xcd * 8 + (loc >> 4)) * 128;
    const int bnIdx = loc & 15;
    const int bn0 = bnIdx * 128;

    const int t8 = tid >> 3, t7 = tid & 7;

#define STAF(BUF, KT) {                                                     \
    _Pragma("unroll") for (int j_ = 0; j_ < 2; ++j_) {                      \
        const int r1_ = j_ * 32 + t8;                                       \
        const int sl_ = (t7 * 2) ^ ((r1_ & 7) << 1);                        \
        const int row_ = 2 * r1_ + (sl_ >> 3);                              \
        const int cb_ = (KT) * 64 + (sl_ & 7) * 8;                          \
        gload16b((const uchar_t*)A + (size_t)(bm0 + row_) * K + cb_,        \
                 &As[BUF][j_ * 4096 + wv * 1024]);                          \
    } }
#define STBF(BUF, KT) {                                                     \
    _Pragma("unroll") for (int j_ = 0; j_ < 2; ++j_) {                      \
        const int r1_ = j_ * 32 + t8;                                       \
        const int sl_ = (t7 * 2) ^ ((r1_ & 7) << 1);                        \
        const int row_ = 2 * r1_ + (sl_ >> 3);                              \
        const int cb_ = (KT) * 64 + (sl_ & 7) * 8;                          \
        gload16b((const uchar_t*)Bt + (size_t)(bn0 + row_) * K + cb_,       \
                 &Bs[BUF][j_ * 4096 + wv * 1024]);                          \
    } }

    auto ldA = [&](int buf, int mf) -> i32x4 {
        const int row = wm * 64 + mf * 16 + fr;
        const int r1 = row >> 1;
        const int phys = (((row & 1) << 3) | (fg << 1)) ^ ((r1 & 7) << 1);
        return *(const i32x4*)&As[buf][r1 * 128 + phys * 8];
    };
    auto ldB = [&](int buf, int nf) -> i32x4 {
        const int row = wn * 64 + nf * 16 + fr;
        const int r1 = row >> 1;
        const int phys = (((row & 1) << 3) | (fg << 1)) ^ ((r1 & 7) << 1);
        return *(const i32x4*)&Bs[buf][r1 * 128 + phys * 8];
    };

    i32x4 acc[4][4] = {};

    STAF(0, 0) STBF(0, 0)
    asm volatile("s_waitcnt vmcnt(0)" ::: "memory");
    CFENCE(); __builtin_amdgcn_s_barrier(); CFENCE();

#define TILEI(BUF, TT) {                                                    \
    const int t_ = (TT);                                                    \
    i32x4 af[4], bf[4];                                                     \
    _Pragma("unroll") for (int n_ = 0; n_ < 4; ++n_) bf[n_] = ldB(BUF, n_); \
    _Pragma("unroll") for (int m_ = 0; m_ < 4; ++m_) af[m_] = ldA(BUF, m_); \
    if (t_ + 1 < NT) { STAF(BUF ^ 1, t_ + 1) STBF(BUF ^ 1, t_ + 1) }        \
    CFENCE(); __builtin_amdgcn_s_barrier(); CFENCE();                       \
    __builtin_amdgcn_s_setprio(1);                                          \
    _Pragma("unroll") for (int m_ = 0; m_ < 4; ++m_)                        \
        _Pragma("unroll") for (int n_ = 0; n_ < 4; ++n_)                    \
            acc[m_][n_] = MFMAI8(acc[m_][n_], af[m_], bf[n_]);              \
    __builtin_amdgcn_s_setprio(0);                                          \
    asm volatile("s_waitcnt vmcnt(0)" ::: "memory");                        \
    CFENCE(); __builtin_amdgcn_s_barrier(); CFENCE();                       \
    }

#pragma unroll 1
    for (int t = 0; t < NT; t += 2) {
        TILEI(0, t)
        TILEI(1, t + 1)
    }
#undef TILEI
#undef STAF
#undef STBF

    __syncthreads();
    float* rsum = (float*)&As[0][0];
#pragma unroll
    for (int m = 0; m < 4; ++m)
#pragma unroll
        for (int r = 0; r < 4; ++r) {
            float s = 0.f;
#pragma unroll
            for (int n = 0; n < 4; ++n) s += fabsf((float)acc[m][n][r]);
            s += __shfl_xor(s, 1); s += __shfl_xor(s, 2);
            s += __shfl_xor(s, 4); s += __shfl_xor(s, 8);
            if (fr == 0) rsum[wn * 128 + wm * 64 + m * 16 + fg * 4 + r] = s;
        }
    __syncthreads();
    if (tid < 128)
        partout[(size_t)bnIdx * NB + bm0 + tid] = rsum[tid] + rsum[128 + tid];
}

// ---------------- per-row kernel: logits, losses, v (i8 out, scaled x800) ----------------
__global__ __launch_bounds__(256) void rows_kernel(const ushort_t* __restrict__ hb,
                                                   const int* __restrict__ y,
                                                   const float* __restrict__ W2,
                                                   const float* __restrict__ b2,
                                                   char* __restrict__ vb,
                                                   float4* __restrict__ rowstats) {
    __shared__ float w2t[NC][NH];
    __shared__ float b2s[NC];
    const int tid = threadIdx.x;
    for (int i = tid; i < NH * NC; i += 256) w2t[i % NC][i / NC] = W2[i];
    if (tid < NC) b2s[tid] = b2[tid];
    __syncthreads();
    const int wid = tid >> 6, lane = tid & 63;
    const int row = blockIdx.x * 4 + wid;
    const ushort_t* hrow = hb + (size_t)row * NH;
    char* vrow = vb + (size_t)row * NH;
    const int yi = y[row];
    float d0 = 0, d1 = 0, d2 = 0, d3 = 0, d4 = 0;
#pragma unroll
    for (int it = 0; it < 2; ++it) {
        const int n0 = it * 512 + lane * 8;
        u16x8 hv = *(const u16x8*)(hrow + n0);
        float hh[8];
#pragma unroll
        for (int j = 0; j < 8; ++j) hh[j] = b2f(hv[j]);
#pragma unroll
        for (int c = 0; c < NC; ++c) {
            const float4 a = *(const float4*)&w2t[c][n0];
            const float4 b = *(const float4*)&w2t[c][n0 + 4];
            float d = hh[0] * a.x; d += hh[1] * a.y; d += hh[2] * a.z; d += hh[3] * a.w;
            d += hh[4] * b.x; d += hh[5] * b.y; d += hh[6] * b.z; d += hh[7] * b.w;
            if (c == 0) d0 += d; else if (c == 1) d1 += d; else if (c == 2) d2 += d;
            else if (c == 3) d3 += d; else d4 += d;
        }
        const float4 ya = *(const float4*)&w2t[yi][n0];
        const float4 yb = *(const float4*)&w2t[yi][n0 + 4];
        const float yw[8] = { ya.x, ya.y, ya.z, ya.w, yb.x, yb.y, yb.z, yb.w };
        union { char b[8]; long l; } ov;
#pragma unroll
        for (int j = 0; j < 8; ++j)
            ov.b[j] = f2i8((1.f - hh[j] * hh[j]) * yw[j], VS_I8);
        *(long*)(vrow + n0) = ov.l;
    }
#pragma unroll
    for (int off = 32; off; off >>= 1) {
        d0 += __shfl_xor(d0, off); d1 += __shfl_xor(d1, off); d2 += __shfl_xor(d2, off);
        d3 += __shfl_xor(d3, off); d4 += __shfl_xor(d4, off);
    }
    if (lane == 0) {
        float lg[NC] = { d0 + b2s[0], d1 + b2s[1], d2 + b2s[2], d3 + b2s[3], d4 + b2s[4] };
        float zy = lg[yi];
        float mse = 0.f, marg = 0.f;
        int amax = 0; float best = lg[0];
#pragma unroll
        for (int c = 0; c < NC; ++c) {
            float t = lg[c] - (c == yi ? 1.f : 0.f);
            mse += t * t;
            if (c != yi) marg += fmaxf(1.f - zy + lg[c], 0.f);
            if (lg[c] > best) { best = lg[c]; amax = c; }
        }
        rowstats[row] = make_float4(zy, mse, marg, (amax == yi) ? 1.f : 0.f);
    }
}

// ---------------- reductions ----------------
__global__ __launch_bounds__(256) void reduce_rows(const float4* __restrict__ rs,
                                                   const float* __restrict__ part,
                                                   int NT, float4* __restrict__ bsums) {
    const int tid = threadIdx.x;
    const int r = blockIdx.x * 256 + tid;
    float4 v = rs[r];
    float wl1 = 0.f;
    for (int t = 0; t < NT; ++t) wl1 += part[(size_t)t * NB + r];
    wl1 *= (1.0f / (VS_I8 * WS_I8));
    float R = wl1 * EPS_C / (fabsf(v.x) + 1e-8f);
    float4 s = make_float4(v.y, v.z, v.w, log1pf(R));
#pragma unroll
    for (int off = 32; off; off >>= 1) {
        s.x += __shfl_down(s.x, off); s.y += __shfl_down(s.y, off);
        s.z += __shfl_down(s.z, off); s.w += __shfl_down(s.w, off);
    }
    __shared__ float4 red[4];
    if ((tid & 63) == 0) red[tid >> 6] = s;
    __syncthreads();
    if (tid == 0) {
        float4 t = red[0];
        for (int i = 1; i < 4; ++i) { t.x += red[i].x; t.y += red[i].y; t.z += red[i].z; t.w += red[i].w; }
        bsums[blockIdx.x] = t;
    }
}

__global__ void final_combine(const float4* __restrict__ bsums, int nb, float* __restrict__ out) {
    const int l = threadIdx.x;
    float4 s = (l < nb) ? bsums[l] : make_float4(0.f, 0.f, 0.f, 0.f);
#pragma unroll
    for (int off = 32; off; off >>= 1) {
        s.x += __shfl_down(s.x, off); s.y += __shfl_down(s.y, off);
        s.z += __shfl_down(s.z, off); s.w += __shfl_down(s.w, off);
    }
    if (l == 0) {
        const float Bf = (float)NB;
        out[0] = s.x / (Bf * (float)NC) + (s.y / Bf + BETA * s.w / Bf) * (s.z / Bf);
    }
}

extern "C" void kernel_launch(void* const* d_in, const int* in_sizes, int n_in,
                              void* d_out, int out_size, void* d_ws, size_t ws_size,
                              hipStream_t stream) {
    const float* x  = (const float*)d_in[0];
    const int*   y  = (const int*)d_in[1];
    const float* W1 = (const float*)d_in[2];
    const float* b1 = (const float*)d_in[3];
    const float* W2 = (const float*)d_in[4];
    const float* b2 = (const float*)d_in[5];
    float* out = (float*)d_out;

    char* ws = (char*)d_ws;
    ushort_t* W1Tb = (ushort_t*)(ws);                           // 4MB
    char*     W1i8 = (char*)(ws + (4ul << 20));                 // 2MB
    ushort_t* hb   = (ushort_t*)(ws + (40ul << 20));            // 16MB
    char*     vi8  = (char*)(ws + (56ul << 20));                // 8MB
    float4*   rowstats = (float4*)(ws + (72ul << 20));          // 128KB
    float*    part = (float*)(ws + (72ul << 20) + (1ul << 20)); // 512KB
    float4*   bsums = (float4*)(ws + (74ul << 20));             // 512B

    // 1. weight conversions (x cast fused into GEMM1)
    trans_kernel<<<dim3(NL / 32, NH / 32), 256, 0, stream>>>(W1, W1Tb, W1i8);

    // 2. GEMM1 (fused f32 A-staging): h = tanh(x @ W1 + b1)
    g128_1f<<<512, 256, 0, stream>>>(x, W1Tb, b1, hb);

    // 3. per-row: logits/mse/margin/zy/correct + v (i8, x800)
    rows_kernel<<<NB / 4, 256, 0, stream>>>(hb, y, W2, b2, vi8, rowstats);

    // 4. GEMM2 (i8 16x16x64): g = v @ W1^T, row |.| partials
    g2i8<<<1024, 256, 0, stream>>>(vi8, W1i8, part);

    // 5. reductions
    reduce_rows<<<NB / 256, 256, 0, stream>>>(rowstats, part, NL / 128, bsums);
    final_combine<<<1, 64, 0, stream>>>(bsums, NB / 256, out);
}

// Round 15
// 102.346 us; speedup vs baseline: 1.3130x; 1.0228x over previous
//
#include <hip/hip_runtime.h>
#include <hip/hip_bf16.h>

typedef unsigned short ushort_t;
typedef unsigned char uchar_t;
typedef __attribute__((ext_vector_type(8))) short short8;
typedef __attribute__((ext_vector_type(8))) unsigned short u16x8;
typedef __attribute__((ext_vector_type(4))) float f32x4;
typedef __attribute__((ext_vector_type(4))) int i32x4;
typedef __attribute__((ext_vector_type(4))) unsigned int u32x4;

#define BETA 0.4f
#define EPS_C 0.05f
#define NB 8192
#define NH 1024
#define NL 2048
#define NC 5
#define VS_I8 800.0f
#define WS_I8 1200.0f

static __device__ __forceinline__ float b2f(unsigned short u) {
    union { unsigned int i; float f; } x; x.i = ((unsigned int)u) << 16; return x.f;
}
static __device__ __forceinline__ unsigned short f2b(float f) {
    union { float f; unsigned int i; } x; x.f = f;
    unsigned int i = x.i;
    unsigned int r = (i + 0x7FFFu + ((i >> 16) & 1u)) >> 16;
    return (unsigned short)r;
}
static __device__ __forceinline__ char f2i8(float f, float s) {
    float q = rintf(f * s);
    q = fminf(127.f, fmaxf(-127.f, q));
    return (char)(int)q;
}
static __device__ __forceinline__ unsigned int cvtpk(float lo, float hi) {
    unsigned int r;
    asm("v_cvt_pk_bf16_f32 %0, %1, %2" : "=v"(r) : "v"(lo), "v"(hi));
    return r;
}

static __device__ __forceinline__ void gload16(const ushort_t* g, ushort_t* l) {
    __builtin_amdgcn_global_load_lds((const __attribute__((address_space(1))) void*)g,
                                     (__attribute__((address_space(3))) void*)l, 16, 0, 0);
}
static __device__ __forceinline__ void gload16b(const uchar_t* g, uchar_t* l) {
    __builtin_amdgcn_global_load_lds((const __attribute__((address_space(1))) void*)g,
                                     (__attribute__((address_space(3))) void*)l, 16, 0, 0);
}

#define CFENCE() asm volatile("" ::: "memory")
#define MFMA16(d, a, b) __builtin_amdgcn_mfma_f32_16x16x32_bf16(a, b, d, 0, 0, 0)
#define MFMAI8(d, a, b) __builtin_amdgcn_mfma_i32_16x16x64_i8(a, b, d, 0, 0, 0)

// W1 [2048,1024] -> W1Tb bf16 [1024,2048]  AND  W1i8 = i8(W1*1200) [2048,1024]
__global__ __launch_bounds__(256) void trans_kernel(const float* __restrict__ W1,
                                                    ushort_t* __restrict__ W1Tb,
                                                    char* __restrict__ W1i8) {
    __shared__ float tile[32][33];
    const int tx = threadIdx.x & 31, ty = threadIdx.x >> 5;
    const int k0 = blockIdx.x * 32, n0 = blockIdx.y * 32;
#pragma unroll
    for (int i = 0; i < 4; ++i) {
        const float v = W1[(size_t)(k0 + ty + i * 8) * NH + n0 + tx];
        tile[ty + i * 8][tx] = v;
        W1i8[(size_t)(k0 + ty + i * 8) * NH + n0 + tx] = f2i8(v, WS_I8);
    }
    __syncthreads();
#pragma unroll
    for (int i = 0; i < 4; ++i)
        W1Tb[(size_t)(n0 + ty + i * 8) * NL + k0 + tx] = f2b(tile[tx][ty + i * 8]);
}

// ==== GEMM1: fused f32->bf16 A-staging, DISTANCE-2 xa prefetch + counted vmcnt ====
// Per tile t: reads(t) -> STB(t+1) -> LDX(t+2) -> barrier -> MFMA -> vmcnt(8)
// [drains xa(t+1)+STB(t+1); keeps xa(t+2) in flight] -> WRX(t+1) -> lgkm(0) -> barrier.
__global__ __launch_bounds__(256, 2) void g128_1p(const float* __restrict__ X,
                                                  const ushort_t* __restrict__ Bt,
                                                  const float* __restrict__ b1,
                                                  ushort_t* __restrict__ hout) {
    constexpr int K  = 2048;
    constexpr int NT = K / 64;          // 32

    __shared__ ushort_t As[2][8192];    // 128 x 64 bf16, 128B rows, XOR-swz slots
    __shared__ ushort_t Bs[2][8192];

    const int tid = threadIdx.x;
    const int wv = tid >> 6, lane = tid & 63;
    const int wm = (wv >> 1) & 1, wn = wv & 1;
    const int fr = lane & 15, fg = lane >> 4;

    const int xcd = blockIdx.x & 7, loc = blockIdx.x >> 3;
    const int bm0 = (xcd * 8 + (loc >> 3)) * 128;
    const int bn0 = (loc & 7) * 128;

    const int srow = lane >> 3;
    const int scolb = ((lane & 7) ^ srow) << 3;   // bf16-elem col (B staging)
    const int scolf = ((lane & 7) ^ srow) * 8;    // f32-elem col (A source)

#define STB(BUF, KT) {                                                      \
    _Pragma("unroll") for (int c_ = 0; c_ < 4; ++c_) {                      \
        const int row_ = c_ * 32 + wv * 8 + srow;                           \
        gload16(Bt + (size_t)(bn0 + row_) * K + (KT) * 64 + scolb,          \
                &Bs[BUF][c_ * 2048 + wv * 512]);                            \
    } }
#define LDX(XA, KT) {                                                       \
    _Pragma("unroll") for (int c_ = 0; c_ < 4; ++c_) {                      \
        const int row_ = c_ * 32 + wv * 8 + srow;                           \
        const float* p_ = X + (size_t)(bm0 + row_) * K + (KT) * 64 + scolf; \
        XA[c_][0] = *(const float4*)p_;                                     \
        XA[c_][1] = *(const float4*)(p_ + 4);                               \
    } }
#define WRX(BUF, XA) {                                                      \
    _Pragma("unroll") for (int c_ = 0; c_ < 4; ++c_) {                      \
        u32x4 w_;                                                           \
        w_[0] = cvtpk(XA[c_][0].x, XA[c_][0].y);                            \
        w_[1] = cvtpk(XA[c_][0].z, XA[c_][0].w);                            \
        w_[2] = cvtpk(XA[c_][1].x, XA[c_][1].y);                            \
        w_[3] = cvtpk(XA[c_][1].z, XA[c_][1].w);                            \
        *(u32x4*)&As[BUF][c_ * 2048 + wv * 512 + lane * 8] = w_;            \
    } }

    auto ldA = [&](int buf, int mf, int ks) -> short8 {
        const int row = wm * 64 + mf * 16 + fr;
        const int slot = ((ks << 2) + fg) ^ (row & 7);
        return *(const short8*)&As[buf][row * 64 + slot * 8];
    };
    auto ldB = [&](int buf, int nf, int ks) -> short8 {
        const int row = wn * 64 + nf * 16 + fr;
        const int slot = ((ks << 2) + fg) ^ (row & 7);
        return *(const short8*)&Bs[buf][row * 64 + slot * 8];
    };

    f32x4 acc[4][4] = {};
    float4 xa0[4][2], xa1[4][2];

    // prologue: A(0) via reg-cvt; B(0); then preload xa0 <- tile 1
    LDX(xa0, 0)
    STB(0, 0)
    asm volatile("s_waitcnt vmcnt(4)" ::: "memory");   // xa0(0) done; STB(0) in flight
    WRX(0, xa0)
    LDX(xa0, 1)
    asm volatile("s_waitcnt vmcnt(8)" ::: "memory");   // drains STB(0); keeps xa0(1)
    asm volatile("s_waitcnt lgkmcnt(0)" ::: "memory");
    CFENCE(); __builtin_amdgcn_s_barrier(); CFENCE();

#define TILE(BUF, XP, XL, TT) {                                             \
    const int t_ = (TT);                                                    \
    short8 af[4][2], bf[4][2];                                              \
    _Pragma("unroll") for (int n_ = 0; n_ < 4; ++n_) {                      \
        bf[n_][0] = ldB(BUF, n_, 0); bf[n_][1] = ldB(BUF, n_, 1);           \
    }                                                                       \
    _Pragma("unroll") for (int m_ = 0; m_ < 4; ++m_) {                      \
        af[m_][0] = ldA(BUF, m_, 0); af[m_][1] = ldA(BUF, m_, 1);           \
    }                                                                       \
    if (t_ + 1 < NT) { STB(BUF ^ 1, t_ + 1) }                               \
    if (t_ + 2 < NT) { LDX(XL, t_ + 2) }                                    \
    CFENCE(); __builtin_amdgcn_s_barrier(); CFENCE();                       \
    __builtin_amdgcn_s_setprio(1);                                          \
    _Pragma("unroll") for (int m_ = 0; m_ < 4; ++m_)                        \
        _Pragma("unroll") for (int n_ = 0; n_ < 4; ++n_) {                  \
            acc[m_][n_] = MFMA16(acc[m_][n_], af[m_][0], bf[n_][0]);        \
            acc[m_][n_] = MFMA16(acc[m_][n_], af[m_][1], bf[n_][1]);        \
        }                                                                   \
    __builtin_amdgcn_s_setprio(0);                                          \
    if (t_ + 2 < NT) { asm volatile("s_waitcnt vmcnt(8)" ::: "memory"); }   \
    else             { asm volatile("s_waitcnt vmcnt(0)" ::: "memory"); }   \
    if (t_ + 1 < NT) { WRX(BUF ^ 1, XP) }                                   \
    asm volatile("s_waitcnt lgkmcnt(0)" ::: "memory");                      \
    CFENCE(); __builtin_amdgcn_s_barrier(); CFENCE();                       \
    }

#pragma unroll 1
    for (int t = 0; t < NT; t += 2) {
        TILE(0, xa0, xa1, t)
        TILE(1, xa1, xa0, t + 1)
    }
#undef TILE
#undef STB
#undef LDX
#undef WRX

#pragma unroll
    for (int m = 0; m < 4; ++m)
#pragma unroll
        for (int n = 0; n < 4; ++n) {
            const int col = bn0 + wn * 64 + n * 16 + fr;
            const float bb = b1[col];
            const size_t rbase = (size_t)(bm0 + wm * 64 + m * 16 + fg * 4) * NH + col;
#pragma unroll
            for (int r = 0; r < 4; ++r)
                hout[rbase + (size_t)r * NH] = f2b(tanhf(acc[m][n][r] + bb));
        }
}

// ============ GEMM2: int8 16x16x64 (r13 proven) ============
__global__ __launch_bounds__(256, 4) void g2i8(const char* __restrict__ A,
                                               const char* __restrict__ Bt,
                                               float* __restrict__ partout) {
    constexpr int K  = 1024;
    constexpr int NT = K / 64;

    __shared__ uchar_t As[2][8192];
    __shared__ uchar_t Bs[2][8192];

    const int tid = threadIdx.x;
    const int wv = tid >> 6, lane = tid & 63;
    const int wm = (wv >> 1) & 1, wn = wv & 1;
    const int fr = lane & 15, fg = lane >> 4;

    const int xcd = blockIdx.x & 7, loc = blockIdx.x >> 3;
    const int bm0 = (xcd * 8 + (loc >> 4)) * 128;
    const int bnIdx = loc & 15;
    const int bn0 = bnIdx * 128;

    const int t8 = tid >> 3, t7 = tid & 7;

#define STAF(BUF, KT) {                                                     \
    _Pragma("unroll") for (int j_ = 0; j_ < 2; ++j_) {                      \
        const int r1_ = j_ * 32 + t8;                                       \
        const int sl_ = (t7 * 2) ^ ((r1_ & 7) << 1);                        \
        const int row_ = 2 * r1_ + (sl_ >> 3);                              \
        const int cb_ = (KT) * 64 + (sl_ & 7) * 8;                          \
        gload16b((const uchar_t*)A + (size_t)(bm0 + row_) * K + cb_,        \
                 &As[BUF][j_ * 4096 + wv * 1024]);                          \
    } }
#define STBF(BUF, KT) {                                                     \
    _Pragma("unroll") for (int j_ = 0; j_ < 2; ++j_) {                      \
        const int r1_ = j_ * 32 + t8;                                       \
        const int sl_ = (t7 * 2) ^ ((r1_ & 7) << 1);                        \
        const int row_ = 2 * r1_ + (sl_ >> 3);                              \
        const int cb_ = (KT) * 64 + (sl_ & 7) * 8;                          \
        gload16b((const uchar_t*)Bt + (size_t)(bm0 ? (bn0 + row_) : (bn0 + row_)) * K + cb_, \
                 &Bs[BUF][j_ * 4096 + wv * 1024]);                          \
    } }

    auto ldA = [&](int buf, int mf) -> i32x4 {
        const int row = wm * 64 + mf * 16 + fr;
        const int r1 = row >> 1;
        const int phys = (((row & 1) << 3) | (fg << 1)) ^ ((r1 & 7) << 1);
        return *(const i32x4*)&As[buf][r1 * 128 + phys * 8];
    };
    auto ldB = [&](int buf, int nf) -> i32x4 {
        const int row = wn * 64 + nf * 16 + fr;
        const int r1 = row >> 1;
        const int phys = (((row & 1) << 3) | (fg << 1)) ^ ((r1 & 7) << 1);
        return *(const i32x4*)&Bs[buf][r1 * 128 + phys * 8];
    };

    i32x4 acc[4][4] = {};

    STAF(0, 0) STBF(0, 0)
    asm volatile("s_waitcnt vmcnt(0)" ::: "memory");
    CFENCE(); __builtin_amdgcn_s_barrier(); CFENCE();

#define TILEI(BUF, TT) {                                                    \
    const int t_ = (TT);                                                    \
    i32x4 af[4], bf[4];                                                     \
    _Pragma("unroll") for (int n_ = 0; n_ < 4; ++n_) bf[n_] = ldB(BUF, n_); \
    _Pragma("unroll") for (int m_ = 0; m_ < 4; ++m_) af[m_] = ldA(BUF, m_); \
    if (t_ + 1 < NT) { STAF(BUF ^ 1, t_ + 1) STBF(BUF ^ 1, t_ + 1) }        \
    CFENCE(); __builtin_amdgcn_s_barrier(); CFENCE();                       \
    __builtin_amdgcn_s_setprio(1);                                          \
    _Pragma("unroll") for (int m_ = 0; m_ < 4; ++m_)                        \
        _Pragma("unroll") for (int n_ = 0; n_ < 4; ++n_)                    \
            acc[m_][n_] = MFMAI8(acc[m_][n_], af[m_], bf[n_]);              \
    __builtin_amdgcn_s_setprio(0);                                          \
    asm volatile("s_waitcnt vmcnt(0)" ::: "memory");                        \
    CFENCE(); __builtin_amdgcn_s_barrier(); CFENCE();                       \
    }

#pragma unroll 1
    for (int t = 0; t < NT; t += 2) {
        TILEI(0, t)
        TILEI(1, t + 1)
    }
#undef TILEI
#undef STAF
#undef STBF

    __syncthreads();
    float* rsum = (float*)&As[0][0];
#pragma unroll
    for (int m = 0; m < 4; ++m)
#pragma unroll
        for (int r = 0; r < 4; ++r) {
            float s = 0.f;
#pragma unroll
            for (int n = 0; n < 4; ++n) s += fabsf((float)acc[m][n][r]);
            s += __shfl_xor(s, 1); s += __shfl_xor(s, 2);
            s += __shfl_xor(s, 4); s += __shfl_xor(s, 8);
            if (fr == 0) rsum[wn * 128 + wm * 64 + m * 16 + fg * 4 + r] = s;
        }
    __syncthreads();
    if (tid < 128)
        partout[(size_t)bnIdx * NB + bm0 + tid] = rsum[tid] + rsum[128 + tid];
}

// ---------------- per-row kernel: logits, losses, v (i8 out, scaled x800) ----------------
__global__ __launch_bounds__(256) void rows_kernel(const ushort_t* __restrict__ hb,
                                                   const int* __restrict__ y,
                                                   const float* __restrict__ W2,
                                                   const float* __restrict__ b2,
                                                   char* __restrict__ vb,
                                                   float4* __restrict__ rowstats) {
    __shared__ float w2t[NC][NH];
    __shared__ float b2s[NC];
    const int tid = threadIdx.x;
    for (int i = tid; i < NH * NC; i += 256) w2t[i % NC][i / NC] = W2[i];
    if (tid < NC) b2s[tid] = b2[tid];
    __syncthreads();
    const int wid = tid >> 6, lane = tid & 63;
    const int row = blockIdx.x * 4 + wid;
    const ushort_t* hrow = hb + (size_t)row * NH;
    char* vrow = vb + (size_t)row * NH;
    const int yi = y[row];
    float d0 = 0, d1 = 0, d2 = 0, d3 = 0, d4 = 0;
#pragma unroll
    for (int it = 0; it < 2; ++it) {
        const int n0 = it * 512 + lane * 8;
        u16x8 hv = *(const u16x8*)(hrow + n0);
        float hh[8];
#pragma unroll
        for (int j = 0; j < 8; ++j) hh[j] = b2f(hv[j]);
#pragma unroll
        for (int c = 0; c < NC; ++c) {
            const float4 a = *(const float4*)&w2t[c][n0];
            const float4 b = *(const float4*)&w2t[c][n0 + 4];
            float d = hh[0] * a.x; d += hh[1] * a.y; d += hh[2] * a.z; d += hh[3] * a.w;
            d += hh[4] * b.x; d += hh[5] * b.y; d += hh[6] * b.z; d += hh[7] * b.w;
            if (c == 0) d0 += d; else if (c == 1) d1 += d; else if (c == 2) d2 += d;
            else if (c == 3) d3 += d; else d4 += d;
        }
        const float4 ya = *(const float4*)&w2t[yi][n0];
        const float4 yb = *(const float4*)&w2t[yi][n0 + 4];
        const float yw[8] = { ya.x, ya.y, ya.z, ya.w, yb.x, yb.y, yb.z, yb.w };
        union { char b[8]; long l; } ov;
#pragma unroll
        for (int j = 0; j < 8; ++j)
            ov.b[j] = f2i8((1.f - hh[j] * hh[j]) * yw[j], VS_I8);
        *(long*)(vrow + n0) = ov.l;
    }
#pragma unroll
    for (int off = 32; off; off >>= 1) {
        d0 += __shfl_xor(d0, off); d1 += __shfl_xor(d1, off); d2 += __shfl_xor(d2, off);
        d3 += __shfl_xor(d3, off); d4 += __shfl_xor(d4, off);
    }
    if (lane == 0) {
        float lg[NC] = { d0 + b2s[0], d1 + b2s[1], d2 + b2s[2], d3 + b2s[3], d4 + b2s[4] };
        float zy = lg[yi];
        float mse = 0.f, marg = 0.f;
        int amax = 0; float best = lg[0];
#pragma unroll
        for (int c = 0; c < NC; ++c) {
            float t = lg[c] - (c == yi ? 1.f : 0.f);
            mse += t * t;
            if (c != yi) marg += fmaxf(1.f - zy + lg[c], 0.f);
            if (lg[c] > best) { best = lg[c]; amax = c; }
        }
        rowstats[row] = make_float4(zy, mse, marg, (amax == yi) ? 1.f : 0.f);
    }
}

// ---------------- reductions ----------------
__global__ __launch_bounds__(256) void reduce_rows(const float4* __restrict__ rs,
                                                   const float* __restrict__ part,
                                                   int NT, float4* __restrict__ bsums) {
    const int tid = threadIdx.x;
    const int r = blockIdx.x * 256 + tid;
    float4 v = rs[r];
    float wl1 = 0.f;
    for (int t = 0; t < NT; ++t) wl1 += part[(size_t)t * NB + r];
    wl1 *= (1.0f / (VS_I8 * WS_I8));
    float R = wl1 * EPS_C / (fabsf(v.x) + 1e-8f);
    float4 s = make_float4(v.y, v.z, v.w, log1pf(R));
#pragma unroll
    for (int off = 32; off; off >>= 1) {
        s.x += __shfl_down(s.x, off); s.y += __shfl_down(s.y, off);
        s.z += __shfl_down(s.z, off); s.w += __shfl_down(s.w, off);
    }
    __shared__ float4 red[4];
    if ((tid & 63) == 0) red[tid >> 6] = s;
    __syncthreads();
    if (tid == 0) {
        float4 t = red[0];
        for (int i = 1; i < 4; ++i) { t.x += red[i].x; t.y += red[i].y; t.z += red[i].z; t.w += red[i].w; }
        bsums[blockIdx.x] = t;
    }
}

__global__ void final_combine(const float4* __restrict__ bsums, int nb, float* __restrict__ out) {
    const int l = threadIdx.x;
    float4 s = (l < nb) ? bsums[l] : make_float4(0.f, 0.f, 0.f, 0.f);
#pragma unroll
    for (int off = 32; off; off >>= 1) {
        s.x += __shfl_down(s.x, off); s.y += __shfl_down(s.y, off);
        s.z += __shfl_down(s.z, off); s.w += __shfl_down(s.w, off);
    }
    if (l == 0) {
        const float Bf = (float)NB;
        out[0] = s.x / (Bf * (float)NC) + (s.y / Bf + BETA * s.w / Bf) * (s.z / Bf);
    }
}

extern "C" void kernel_launch(void* const* d_in, const int* in_sizes, int n_in,
                              void* d_out, int out_size, void* d_ws, size_t ws_size,
                              hipStream_t stream) {
    const float* x  = (const float*)d_in[0];
    const int*   y  = (const int*)d_in[1];
    const float* W1 = (const float*)d_in[2];
    const float* b1 = (const float*)d_in[3];
    const float* W2 = (const float*)d_in[4];
    const float* b2 = (const float*)d_in[5];
    float* out = (float*)d_out;

    char* ws = (char*)d_ws;
    ushort_t* W1Tb = (ushort_t*)(ws);                           // 4MB
    char*     W1i8 = (char*)(ws + (4ul << 20));                 // 2MB
    ushort_t* hb   = (ushort_t*)(ws + (40ul << 20));            // 16MB
    char*     vi8  = (char*)(ws + (56ul << 20));                // 8MB
    float4*   rowstats = (float4*)(ws + (72ul << 20));          // 128KB
    float*    part = (float*)(ws + (72ul << 20) + (1ul << 20)); // 512KB
    float4*   bsums = (float4*)(ws + (74ul << 20));             // 512B

    // 1. weight conversions (x cast fused into GEMM1)
    trans_kernel<<<dim3(NL / 32, NH / 32), 256, 0, stream>>>(W1, W1Tb, W1i8);

    // 2. GEMM1 (fused A-staging, distance-2 + counted vmcnt): h = tanh(x @ W1 + b1)
    g128_1p<<<512, 256, 0, stream>>>(x, W1Tb, b1, hb);

    // 3. per-row: logits/mse/margin/zy/correct + v (i8, x800)
    rows_kernel<<<NB / 4, 256, 0, stream>>>(hb, y, W2, b2, vi8, rowstats);

    // 4. GEMM2 (i8 16x16x64): g = v @ W1^T, row |.| partials
    g2i8<<<1024, 256, 0, stream>>>(vi8, W1i8, part);

    // 5. reductions
    reduce_rows<<<NB / 256, 256, 0, stream>>>(rowstats, part, NL / 128, bsums);
    final_combine<<<1, 64, 0, stream>>>(bsums, NB / 256, out);
}

// Round 16
// 92.872 us; speedup vs baseline: 1.4470x; 1.1020x over previous
//
#include <hip/hip_runtime.h>
#include <hip/hip_bf16.h>

typedef unsigned short ushort_t;
typedef unsigned char uchar_t;
typedef __attribute__((ext_vector_type(8))) short short8;
typedef __attribute__((ext_vector_type(8))) unsigned short u16x8;
typedef __attribute__((ext_vector_type(4))) float f32x4;
typedef __attribute__((ext_vector_type(4))) int i32x4;

#define BETA 0.4f
#define EPS_C 0.05f
#define NB 8192
#define NH 1024
#define NL 2048
#define NC 5
#define VS_I8 800.0f
#define WS_I8 1200.0f
#define XS_I8 32.0f
#define G1_INV (1.0f / (XS_I8 * WS_I8))

static __device__ __forceinline__ float b2f(unsigned short u) {
    union { unsigned int i; float f; } x; x.i = ((unsigned int)u) << 16; return x.f;
}
static __device__ __forceinline__ unsigned short f2b(float f) {
    union { float f; unsigned int i; } x; x.f = f;
    unsigned int i = x.i;
    unsigned int r = (i + 0x7FFFu + ((i >> 16) & 1u)) >> 16;
    return (unsigned short)r;
}
static __device__ __forceinline__ char f2i8(float f, float s) {
    float q = rintf(f * s);
    q = fminf(127.f, fmaxf(-127.f, q));
    return (char)(int)q;
}

static __device__ __forceinline__ void gload16b(const uchar_t* g, uchar_t* l) {
    __builtin_amdgcn_global_load_lds((const __attribute__((address_space(1))) void*)g,
                                     (__attribute__((address_space(3))) void*)l, 16, 0, 0);
}

#define CFENCE() asm volatile("" ::: "memory")
#define MFMAI8(d, a, b) __builtin_amdgcn_mfma_i32_16x16x64_i8(a, b, d, 0, 0, 0)

// ---------------- x f32 -> i8 (x * 32) ----------------
__global__ __launch_bounds__(256) void cvt8_kernel(const float* __restrict__ in,
                                                   char* __restrict__ out, long n) {
    long i = ((long)blockIdx.x * 256 + threadIdx.x) * 16;
    if (i >= n) return;
    union { char b[16]; i32x4 v; } o;
#pragma unroll
    for (int q = 0; q < 4; ++q) {
        const float4 a = *(const float4*)(in + i + q * 4);
        o.b[q * 4 + 0] = f2i8(a.x, XS_I8);
        o.b[q * 4 + 1] = f2i8(a.y, XS_I8);
        o.b[q * 4 + 2] = f2i8(a.z, XS_I8);
        o.b[q * 4 + 3] = f2i8(a.w, XS_I8);
    }
    *(i32x4*)(out + i) = o.v;
}

// W1 [2048,1024] -> W1Ti8 [1024,2048] AND W1i8 [2048,1024], both i8 * 1200
__global__ __launch_bounds__(256) void trans_kernel(const float* __restrict__ W1,
                                                    char* __restrict__ W1Ti8,
                                                    char* __restrict__ W1i8) {
    __shared__ float tile[32][33];
    const int tx = threadIdx.x & 31, ty = threadIdx.x >> 5;
    const int k0 = blockIdx.x * 32, n0 = blockIdx.y * 32;
#pragma unroll
    for (int i = 0; i < 4; ++i) {
        const float v = W1[(size_t)(k0 + ty + i * 8) * NH + n0 + tx];
        tile[ty + i * 8][tx] = v;
        W1i8[(size_t)(k0 + ty + i * 8) * NH + n0 + tx] = f2i8(v, WS_I8);
    }
    __syncthreads();
#pragma unroll
    for (int i = 0; i < 4; ++i)
        W1Ti8[(size_t)(n0 + ty + i * 8) * NL + k0 + tx] = f2i8(tile[tx][ty + i * 8], WS_I8);
}

// ============ i8 GEMM template (clone of proven g2i8), 128x128, BK=64 ============
// EPI 0: GEMM1  A=xi8[8192,2048] Bt=W1Ti8[1024,2048]  grid 512, tanh -> hout bf16
// EPI 1: GEMM2  A=vi8[8192,1024] Bt=W1i8 [2048,1024]  grid 1024, row |.| partials
template <int EPI>
__global__ __launch_bounds__(256, 4) void gi8(const char* __restrict__ A,
                                              const char* __restrict__ Bt,
                                              const float* __restrict__ b1,
                                              ushort_t* __restrict__ hout,
                                              float* __restrict__ partout) {
    constexpr int K  = (EPI == 0) ? 2048 : 1024;
    constexpr int NT = K / 64;                  // 32 / 16

    __shared__ uchar_t As[2][8192];             // 128 rows x 64B, pair-packed 128B lines
    __shared__ uchar_t Bs[2][8192];

    const int tid = threadIdx.x;
    const int wv = tid >> 6, lane = tid & 63;
    const int wm = (wv >> 1) & 1, wn = wv & 1;  // wave tile 64x64
    const int fr = lane & 15, fg = lane >> 4;

    const int xcd = blockIdx.x & 7, loc = blockIdx.x >> 3;
    const int bm0 = (EPI == 0) ? (xcd * 8 + (loc >> 3)) * 128
                               : (xcd * 8 + (loc >> 4)) * 128;
    const int bnIdx = (EPI == 0) ? (loc & 7) : (loc & 15);
    const int bn0 = bnIdx * 128;

    const int t8 = tid >> 3, t7 = tid & 7;

#define STAF(BUF, KT) {                                                     \
    _Pragma("unroll") for (int j_ = 0; j_ < 2; ++j_) {                      \
        const int r1_ = j_ * 32 + t8;                                       \
        const int sl_ = (t7 * 2) ^ ((r1_ & 7) << 1);                        \
        const int row_ = 2 * r1_ + (sl_ >> 3);                              \
        const int cb_ = (KT) * 64 + (sl_ & 7) * 8;                          \
        gload16b((const uchar_t*)A + (size_t)(bm0 + row_) * K + cb_,        \
                 &As[BUF][j_ * 4096 + wv * 1024]);                          \
    } }
#define STBF(BUF, KT) {                                                     \
    _Pragma("unroll") for (int j_ = 0; j_ < 2; ++j_) {                      \
        const int r1_ = j_ * 32 + t8;                                       \
        const int sl_ = (t7 * 2) ^ ((r1_ & 7) << 1);                        \
        const int row_ = 2 * r1_ + (sl_ >> 3);                              \
        const int cb_ = (KT) * 64 + (sl_ & 7) * 8;                          \
        gload16b((const uchar_t*)Bt + (size_t)(bn0 + row_) * K + cb_,       \
                 &Bs[BUF][j_ * 4096 + wv * 1024]);                          \
    } }

    auto ldA = [&](int buf, int mf) -> i32x4 {
        const int row = wm * 64 + mf * 16 + fr;
        const int r1 = row >> 1;
        const int phys = (((row & 1) << 3) | (fg << 1)) ^ ((r1 & 7) << 1);
        return *(const i32x4*)&As[buf][r1 * 128 + phys * 8];
    };
    auto ldB = [&](int buf, int nf) -> i32x4 {
        const int row = wn * 64 + nf * 16 + fr;
        const int r1 = row >> 1;
        const int phys = (((row & 1) << 3) | (fg << 1)) ^ ((r1 & 7) << 1);
        return *(const i32x4*)&Bs[buf][r1 * 128 + phys * 8];
    };

    i32x4 acc[4][4] = {};

    STAF(0, 0) STBF(0, 0)
    asm volatile("s_waitcnt vmcnt(0)" ::: "memory");
    CFENCE(); __builtin_amdgcn_s_barrier(); CFENCE();

#define TILEI(BUF, TT) {                                                    \
    const int t_ = (TT);                                                    \
    i32x4 af[4], bf[4];                                                     \
    _Pragma("unroll") for (int n_ = 0; n_ < 4; ++n_) bf[n_] = ldB(BUF, n_); \
    _Pragma("unroll") for (int m_ = 0; m_ < 4; ++m_) af[m_] = ldA(BUF, m_); \
    if (t_ + 1 < NT) { STAF(BUF ^ 1, t_ + 1) STBF(BUF ^ 1, t_ + 1) }        \
    CFENCE(); __builtin_amdgcn_s_barrier(); CFENCE();                       \
    __builtin_amdgcn_s_setprio(1);                                          \
    _Pragma("unroll") for (int m_ = 0; m_ < 4; ++m_)                        \
        _Pragma("unroll") for (int n_ = 0; n_ < 4; ++n_)                    \
            acc[m_][n_] = MFMAI8(acc[m_][n_], af[m_], bf[n_]);              \
    __builtin_amdgcn_s_setprio(0);                                          \
    asm volatile("s_waitcnt vmcnt(0)" ::: "memory");                        \
    CFENCE(); __builtin_amdgcn_s_barrier(); CFENCE();                       \
    }

#pragma unroll 1
    for (int t = 0; t < NT; t += 2) {
        TILEI(0, t)
        TILEI(1, t + 1)
    }
#undef TILEI
#undef STAF
#undef STBF

    if constexpr (EPI == 0) {
#pragma unroll
        for (int m = 0; m < 4; ++m)
#pragma unroll
            for (int n = 0; n < 4; ++n) {
                const int col = bn0 + wn * 64 + n * 16 + fr;
                const float bb = b1[col];
                const size_t rbase = (size_t)(bm0 + wm * 64 + m * 16 + fg * 4) * NH + col;
#pragma unroll
                for (int r = 0; r < 4; ++r)
                    hout[rbase + (size_t)r * NH] =
                        f2b(tanhf((float)acc[m][n][r] * G1_INV + bb));
            }
    } else {
        __syncthreads();
        float* rsum = (float*)&As[0][0];
#pragma unroll
        for (int m = 0; m < 4; ++m)
#pragma unroll
            for (int r = 0; r < 4; ++r) {
                float s = 0.f;
#pragma unroll
                for (int n = 0; n < 4; ++n) s += fabsf((float)acc[m][n][r]);
                s += __shfl_xor(s, 1); s += __shfl_xor(s, 2);
                s += __shfl_xor(s, 4); s += __shfl_xor(s, 8);
                if (fr == 0) rsum[wn * 128 + wm * 64 + m * 16 + fg * 4 + r] = s;
            }
        __syncthreads();
        if (tid < 128)
            partout[(size_t)bnIdx * NB + bm0 + tid] = rsum[tid] + rsum[128 + tid];
    }
}

// ---------------- per-row kernel: logits, losses, v (i8 out, scaled x800) ----------------
__global__ __launch_bounds__(256) void rows_kernel(const ushort_t* __restrict__ hb,
                                                   const int* __restrict__ y,
                                                   const float* __restrict__ W2,
                                                   const float* __restrict__ b2,
                                                   char* __restrict__ vb,
                                                   float4* __restrict__ rowstats) {
    __shared__ float w2t[NC][NH];
    __shared__ float b2s[NC];
    const int tid = threadIdx.x;
    for (int i = tid; i < NH * NC; i += 256) w2t[i % NC][i / NC] = W2[i];
    if (tid < NC) b2s[tid] = b2[tid];
    __syncthreads();
    const int wid = tid >> 6, lane = tid & 63;
    const int row = blockIdx.x * 4 + wid;
    const ushort_t* hrow = hb + (size_t)row * NH;
    char* vrow = vb + (size_t)row * NH;
    const int yi = y[row];
    float d0 = 0, d1 = 0, d2 = 0, d3 = 0, d4 = 0;
#pragma unroll
    for (int it = 0; it < 2; ++it) {
        const int n0 = it * 512 + lane * 8;
        u16x8 hv = *(const u16x8*)(hrow + n0);
        float hh[8];
#pragma unroll
        for (int j = 0; j < 8; ++j) hh[j] = b2f(hv[j]);
#pragma unroll
        for (int c = 0; c < NC; ++c) {
            const float4 a = *(const float4*)&w2t[c][n0];
            const float4 b = *(const float4*)&w2t[c][n0 + 4];
            float d = hh[0] * a.x; d += hh[1] * a.y; d += hh[2] * a.z; d += hh[3] * a.w;
            d += hh[4] * b.x; d += hh[5] * b.y; d += hh[6] * b.z; d += hh[7] * b.w;
            if (c == 0) d0 += d; else if (c == 1) d1 += d; else if (c == 2) d2 += d;
            else if (c == 3) d3 += d; else d4 += d;
        }
        const float4 ya = *(const float4*)&w2t[yi][n0];
        const float4 yb = *(const float4*)&w2t[yi][n0 + 4];
        const float yw[8] = { ya.x, ya.y, ya.z, ya.w, yb.x, yb.y, yb.z, yb.w };
        union { char b[8]; long l; } ov;
#pragma unroll
        for (int j = 0; j < 8; ++j)
            ov.b[j] = f2i8((1.f - hh[j] * hh[j]) * yw[j], VS_I8);
        *(long*)(vrow + n0) = ov.l;
    }
#pragma unroll
    for (int off = 32; off; off >>= 1) {
        d0 += __shfl_xor(d0, off); d1 += __shfl_xor(d1, off); d2 += __shfl_xor(d2, off);
        d3 += __shfl_xor(d3, off); d4 += __shfl_xor(d4, off);
    }
    if (lane == 0) {
        float lg[NC] = { d0 + b2s[0], d1 + b2s[1], d2 + b2s[2], d3 + b2s[3], d4 + b2s[4] };
        float zy = lg[yi];
        float mse = 0.f, marg = 0.f;
        int amax = 0; float best = lg[0];
#pragma unroll
        for (int c = 0; c < NC; ++c) {
            float t = lg[c] - (c == yi ? 1.f : 0.f);
            mse += t * t;
            if (c != yi) marg += fmaxf(1.f - zy + lg[c], 0.f);
            if (lg[c] > best) { best = lg[c]; amax = c; }
        }
        rowstats[row] = make_float4(zy, mse, marg, (amax == yi) ? 1.f : 0.f);
    }
}

// ---------------- reductions ----------------
__global__ __launch_bounds__(256) void reduce_rows(const float4* __restrict__ rs,
                                                   const float* __restrict__ part,
                                                   int NT, float4* __restrict__ bsums) {
    const int tid = threadIdx.x;
    const int r = blockIdx.x * 256 + tid;
    float4 v = rs[r];
    float wl1 = 0.f;
    for (int t = 0; t < NT; ++t) wl1 += part[(size_t)t * NB + r];
    wl1 *= (1.0f / (VS_I8 * WS_I8));
    float R = wl1 * EPS_C / (fabsf(v.x) + 1e-8f);
    float4 s = make_float4(v.y, v.z, v.w, log1pf(R));
#pragma unroll
    for (int off = 32; off; off >>= 1) {
        s.x += __shfl_down(s.x, off); s.y += __shfl_down(s.y, off);
        s.z += __shfl_down(s.z, off); s.w += __shfl_down(s.w, off);
    }
    __shared__ float4 red[4];
    if ((tid & 63) == 0) red[tid >> 6] = s;
    __syncthreads();
    if (tid == 0) {
        float4 t = red[0];
        for (int i = 1; i < 4; ++i) { t.x += red[i].x; t.y += red[i].y; t.z += red[i].z; t.w += red[i].w; }
        bsums[blockIdx.x] = t;
    }
}

__global__ void final_combine(const float4* __restrict__ bsums, int nb, float* __restrict__ out) {
    const int l = threadIdx.x;
    float4 s = (l < nb) ? bsums[l] : make_float4(0.f, 0.f, 0.f, 0.f);
#pragma unroll
    for (int off = 32; off; off >>= 1) {
        s.x += __shfl_down(s.x, off); s.y += __shfl_down(s.y, off);
        s.z += __shfl_down(s.z, off); s.w += __shfl_down(s.w, off);
    }
    if (l == 0) {
        const float Bf = (float)NB;
        out[0] = s.x / (Bf * (float)NC) + (s.y / Bf + BETA * s.w / Bf) * (s.z / Bf);
    }
}

extern "C" void kernel_launch(void* const* d_in, const int* in_sizes, int n_in,
                              void* d_out, int out_size, void* d_ws, size_t ws_size,
                              hipStream_t stream) {
    const float* x  = (const float*)d_in[0];
    const int*   y  = (const int*)d_in[1];
    const float* W1 = (const float*)d_in[2];
    const float* b1 = (const float*)d_in[3];
    const float* W2 = (const float*)d_in[4];
    const float* b2 = (const float*)d_in[5];
    float* out = (float*)d_out;

    char* ws = (char*)d_ws;
    char*     W1Ti8 = (char*)(ws);                              // 2MB
    char*     W1i8  = (char*)(ws + (4ul << 20));                // 2MB
    char*     xi8   = (char*)(ws + (8ul << 20));                // 16MB
    ushort_t* hb    = (ushort_t*)(ws + (40ul << 20));           // 16MB
    char*     vi8   = (char*)(ws + (56ul << 20));               // 8MB
    float4*   rowstats = (float4*)(ws + (72ul << 20));          // 128KB
    float*    part = (float*)(ws + (72ul << 20) + (1ul << 20)); // 512KB
    float4*   bsums = (float4*)(ws + (74ul << 20));             // 512B

    // 1. conversions: x -> i8(x*32); W1 -> i8 both orientations
    cvt8_kernel<<<(NB * (long)NL) / (256 * 16), 256, 0, stream>>>(x, xi8, (long)NB * NL);
    trans_kernel<<<dim3(NL / 32, NH / 32), 256, 0, stream>>>(W1, W1Ti8, W1i8);

    // 2. GEMM1 (i8, g2i8-clone): h = tanh(x @ W1 + b1)
    gi8<0><<<512, 256, 0, stream>>>(xi8, W1Ti8, b1, hb, nullptr);

    // 3. per-row: logits/mse/margin/zy/correct + v (i8, x800)
    rows_kernel<<<NB / 4, 256, 0, stream>>>(hb, y, W2, b2, vi8, rowstats);

    // 4. GEMM2 (i8): g = v @ W1^T, row |.| partials
    gi8<1><<<1024, 256, 0, stream>>>(vi8, W1i8, nullptr, nullptr, part);

    // 5. reductions
    reduce_rows<<<NB / 256, 256, 0, stream>>>(rowstats, part, NL / 128, bsums);
    final_combine<<<1, 64, 0, stream>>>(bsums, NB / 256, out);
}